// Round 5
// baseline (478.722 us; speedup 1.0000x reference)
//
#include <hip/hip_runtime.h>
#include <hip/hip_bf16.h>
#include <stdint.h>

#define D_MODEL 1024
#define D_STATE 16
#define D_CONV 4
#define D_INNER 2048
#define DT_RANK 64
#define BATCH 2
#define SEQ 2048
#define NROW (BATCH * SEQ)          // 4096
#define XPROJ_N (DT_RANK + 2 * D_STATE)  // 96
#define NCHUNK 64                   // time chunks for scan decomposition
#define CL 32                       // SEQ / NCHUNK

typedef __bf16 bf16x8 __attribute__((ext_vector_type(8)));
typedef float  f32x4  __attribute__((ext_vector_type(4)));

// RNE f32 -> bf16 (bit trick; inputs are tame, no NaN handling needed)
__device__ __forceinline__ uint16_t f2bf(float f) {
    uint32_t u = __float_as_uint(f);
    u += 0x7FFFu + ((u >> 16) & 1u);
    return (uint16_t)(u >> 16);
}
__device__ __forceinline__ float bf2f(uint16_t h) {
    return __uint_as_float((uint32_t)h << 16);
}

#define GLOAD_LDS(g, l) __builtin_amdgcn_global_load_lds(                      \
    (const __attribute__((address_space(1))) void*)(g),                        \
    (__attribute__((address_space(3))) void*)(l), 16, 0, 0)

// ---------------------------------------------------------------------------
// bf16 MFMA GEMM, m97 structure: C(MxN,f32) = A(MxK,bf16) @ B(KxN) with B
// given TRANSPOSED (BT is N x K). 128xBN tile, BK=32, 4 waves.
//   BN=128: 2x2 waves, wave tile 64x64 (4x4 frags)
//   BN=64 : 4x1 waves, wave tile 32x64 (2x4 frags)  -- for skinny N
// global_load_lds(16B) staging, ds_read_b128 frags, mfma_f32_16x16x32_bf16.
// XCD-chunked block swizzle: each XCD gets a contiguous stripe of the
// x-fast (bm-fast) ordering -> its few B-panels go L2-resident.
// ---------------------------------------------------------------------------
template <int BN>
__global__ __launch_bounds__(256) void gemm_bf16_bt(const uint16_t* __restrict__ A,
                                                    const uint16_t* __restrict__ BT,
                                                    float* __restrict__ C,
                                                    int M, int N, int K) {
    constexpr int WROWS = (BN == 128) ? 64 : 32;    // rows per wave
    constexpr int MF = WROWS / 16;                  // m-frags per wave
    __shared__ uint16_t sA[128 * 32];               // [row][k], 64B rows
    __shared__ uint16_t sB[BN * 32];                // [n][k]
    const int tid  = threadIdx.x;
    const int wave = tid >> 6;          // 0..3
    const int lane = tid & 63;
    const int wm = (BN == 128) ? (wave >> 1) : wave;
    const int wn = (BN == 128) ? (wave & 1) : 0;

    // XCD-chunked swizzle (nwg multiple of 8)
    const int nwg = gridDim.x * gridDim.y;
    const int bid = blockIdx.y * gridDim.x + blockIdx.x;
    const int orig = (bid & 7) * (nwg >> 3) + (bid >> 3);
    const int bm = (orig % gridDim.x) * 128;
    const int bn = (orig / gridDim.x) * BN;

    // staging: lane covers 16B: row = seg_base + (lane>>2), col = (lane&3)*8
    const int lrow = lane >> 2;
    const int lcol = (lane & 3) * 8;
    const uint16_t* gA0 = A + (size_t)(bm + wave * 32 + lrow) * K + lcol;
    const uint16_t* gA1 = gA0 + (size_t)16 * K;
    uint16_t* lA0 = sA + (wave * 2 + 0) * 512;
    uint16_t* lA1 = sA + (wave * 2 + 1) * 512;
    const uint16_t* gB0;
    const uint16_t* gB1 = nullptr;
    uint16_t* lB0;
    uint16_t* lB1 = nullptr;
    if constexpr (BN == 128) {
        gB0 = BT + (size_t)(bn + wave * 32 + lrow) * K + lcol;
        gB1 = gB0 + (size_t)16 * K;
        lB0 = sB + (wave * 2 + 0) * 512;
        lB1 = sB + (wave * 2 + 1) * 512;
    } else {
        gB0 = BT + (size_t)(bn + wave * 16 + lrow) * K + lcol;
        lB0 = sB + wave * 512;
    }

    const int fr = lane & 15;           // frag row (A: m-row, B: n-col)
    const int fg = lane >> 4;           // frag k-group

    f32x4 acc[MF][4] = {};

    for (int k0 = 0; k0 < K; k0 += 32) {
        GLOAD_LDS(gA0 + k0, lA0);
        GLOAD_LDS(gA1 + k0, lA1);
        GLOAD_LDS(gB0 + k0, lB0);
        if constexpr (BN == 128) GLOAD_LDS(gB1 + k0, lB1);
        __syncthreads();                 // drains vmcnt before barrier

        bf16x8 af[MF], bfr[4];
#pragma unroll
        for (int m = 0; m < MF; ++m)
            af[m] = *(const bf16x8*)&sA[(wm * WROWS + m * 16 + fr) * 32 + fg * 8];
#pragma unroll
        for (int n = 0; n < 4; ++n)
            bfr[n] = *(const bf16x8*)&sB[(wn * 64 + n * 16 + fr) * 32 + fg * 8];
#pragma unroll
        for (int m = 0; m < MF; ++m)
#pragma unroll
            for (int n = 0; n < 4; ++n)
                acc[m][n] = __builtin_amdgcn_mfma_f32_16x16x32_bf16(
                    af[m], bfr[n], acc[m][n], 0, 0, 0);
        __syncthreads();
    }

    // C/D layout: col = lane&15, row = (lane>>4)*4 + reg  [m89-verified]
#pragma unroll
    for (int m = 0; m < MF; ++m)
#pragma unroll
        for (int n = 0; n < 4; ++n) {
            const int col = bn + wn * 64 + n * 16 + fr;
#pragma unroll
            for (int r = 0; r < 4; ++r) {
                const int row = bm + wm * WROWS + m * 16 + fg * 4 + r;
                C[(size_t)row * N + col] = acc[m][n][r];
            }
        }
}

// ---------------------------------------------------------------------------
// x (4096x1024 f32) -> A' (4096x3072 bf16) = [hi | lo | hi]
// ---------------------------------------------------------------------------
__global__ __launch_bounds__(256) void cvt_x_split(const float* __restrict__ x,
                                                   uint16_t* __restrict__ a1) {
    const int i = blockIdx.x * 256 + threadIdx.x;    // float4 index
    const int m = i >> 8;                            // 256 float4 per row
    const int c = (i & 255) << 2;
    const float4 v = ((const float4*)x)[i];
    uint16_t h[4], l[4];
    const float vf[4] = {v.x, v.y, v.z, v.w};
#pragma unroll
    for (int j = 0; j < 4; ++j) {
        h[j] = f2bf(vf[j]);
        l[j] = f2bf(vf[j] - bf2f(h[j]));
    }
    const size_t base = (size_t)m * 3072 + c;
    *(ushort4*)&a1[base]        = *(ushort4*)h;
    *(ushort4*)&a1[base + 1024] = *(ushort4*)l;
    *(ushort4*)&a1[base + 2048] = *(ushort4*)h;
}

// ---------------------------------------------------------------------------
// in_proj_w (1024x4096 f32) -> B'T (4096x3072 bf16): B'T[n][*] = [hi | hi | lo]
// of column n. 32x32 LDS transpose tiles.
// ---------------------------------------------------------------------------
__global__ __launch_bounds__(256) void cvt_wT_split(const float* __restrict__ w,
                                                    uint16_t* __restrict__ bt) {
    __shared__ float s[32][33];
    const int tid = threadIdx.x;
    const int k0 = blockIdx.x * 32;   // source row tile (K dim)
    const int n0 = blockIdx.y * 32;   // source col tile (N dim)
#pragma unroll
    for (int p = 0; p < 4; ++p) {
        int lin = tid + p * 256;
        int i = lin >> 5, j = lin & 31;
        s[i][j] = w[(size_t)(k0 + i) * 4096 + n0 + j];
    }
    __syncthreads();
    const int r = tid >> 3, c4 = (tid & 7) * 4;      // r: n-local, c4: k-local
    uint16_t h[4], l[4];
#pragma unroll
    for (int j = 0; j < 4; ++j) {
        float v = s[c4 + j][r];
        h[j] = f2bf(v);
        l[j] = f2bf(v - bf2f(h[j]));
    }
    const size_t base = (size_t)(n0 + r) * 3072 + k0 + c4;
    *(ushort4*)&bt[base]        = *(ushort4*)h;
    *(ushort4*)&bt[base + 1024] = *(ushort4*)h;
    *(ushort4*)&bt[base + 2048] = *(ushort4*)l;
}

// ---------------------------------------------------------------------------
// out_proj_w (2048x1024 f32) -> opwT (1024x2048 bf16), plain hi.
// ---------------------------------------------------------------------------
__global__ __launch_bounds__(256) void cvt_opwT(const float* __restrict__ w,
                                                uint16_t* __restrict__ bt) {
    __shared__ float s[32][33];
    const int tid = threadIdx.x;
    const int k0 = blockIdx.x * 32;   // source row tile (K=2048 dim)
    const int n0 = blockIdx.y * 32;   // source col tile (N=1024 dim)
#pragma unroll
    for (int p = 0; p < 4; ++p) {
        int lin = tid + p * 256;
        int i = lin >> 5, j = lin & 31;
        s[i][j] = w[(size_t)(k0 + i) * 1024 + n0 + j];
    }
    __syncthreads();
    const int r = tid >> 3, c4 = (tid & 7) * 4;
    uint16_t h[4];
#pragma unroll
    for (int j = 0; j < 4; ++j) h[j] = f2bf(s[c4 + j][r]);
    *(ushort4*)&bt[(size_t)(n0 + r) * 2048 + k0 + c4] = *(ushort4*)h;
}

// ---------------------------------------------------------------------------
// Causal depthwise conv (D_CONV=4) + bias + SiLU.
// ---------------------------------------------------------------------------
__global__ __launch_bounds__(256) void conv_silu(const float* __restrict__ xz,
                                                 const float* __restrict__ conv_w,
                                                 const float* __restrict__ conv_b,
                                                 float* __restrict__ xc_act) {
    int idx = blockIdx.x * 256 + threadIdx.x;       // over NROW*D_INNER
    int d = idx & (D_INNER - 1);
    int r = idx >> 11;                               // b*SEQ + t
    int t = r & (SEQ - 1);
    float acc = conv_b[d];
#pragma unroll
    for (int k = 0; k < D_CONV; ++k) {
        int tt = t + k - (D_CONV - 1);
        if (tt >= 0)
            acc = fmaf(xz[(size_t)(r + k - (D_CONV - 1)) * (2 * D_INNER) + d],
                       conv_w[d * D_CONV + k], acc);
    }
    float s = acc / (1.f + __expf(-acc));            // silu
    xc_act[(size_t)r * D_INNER + d] = s;
}

// ---------------------------------------------------------------------------
// x_dbl = xc_act (NROW x D_INNER) @ x_proj_w (D_INNER x 96). BM=32, full N=96.
// ---------------------------------------------------------------------------
__global__ __launch_bounds__(256) void xdbl_gemm(const float* __restrict__ A,
                                                 const float* __restrict__ W,
                                                 float* __restrict__ out) {
    __shared__ float As[32][132];    // [row][k], +4 pad
    __shared__ float Ws[128][96];    // [k][col]
    const int tid = threadIdx.x;
    const int bm = blockIdx.x * 32;
    const int tc = tid & 31;         // cols tc*3 .. +2
    const int tr = tid >> 5;         // rows tr*4 .. +3
    float acc[4][3];
#pragma unroll
    for (int i = 0; i < 4; ++i)
#pragma unroll
        for (int j = 0; j < 3; ++j) acc[i][j] = 0.f;

    for (int k0 = 0; k0 < D_INNER; k0 += 128) {
#pragma unroll
        for (int l = 0; l < 4; ++l) {                 // A tile 32x128
            int i = tid + l * 256;
            int r = i >> 5, c4 = (i & 31) << 2;
            *(float4*)&As[r][c4] = *(const float4*)(A + (size_t)(bm + r) * D_INNER + k0 + c4);
        }
#pragma unroll
        for (int l = 0; l < 12; ++l) {                // W tile 128x96
            int i = tid + l * 256;
            int r = i / 24, c4 = (i % 24) << 2;
            *(float4*)&Ws[r][c4] = *(const float4*)(W + (size_t)(k0 + r) * XPROJ_N + c4);
        }
        __syncthreads();
#pragma unroll 8
        for (int k = 0; k < 128; ++k) {
            float a0 = As[tr * 4 + 0][k], a1 = As[tr * 4 + 1][k];
            float a2 = As[tr * 4 + 2][k], a3 = As[tr * 4 + 3][k];
            float w0 = Ws[k][tc * 3 + 0], w1 = Ws[k][tc * 3 + 1], w2 = Ws[k][tc * 3 + 2];
            acc[0][0] = fmaf(a0, w0, acc[0][0]); acc[0][1] = fmaf(a0, w1, acc[0][1]); acc[0][2] = fmaf(a0, w2, acc[0][2]);
            acc[1][0] = fmaf(a1, w0, acc[1][0]); acc[1][1] = fmaf(a1, w1, acc[1][1]); acc[1][2] = fmaf(a1, w2, acc[1][2]);
            acc[2][0] = fmaf(a2, w0, acc[2][0]); acc[2][1] = fmaf(a2, w1, acc[2][1]); acc[2][2] = fmaf(a2, w2, acc[2][2]);
            acc[3][0] = fmaf(a3, w0, acc[3][0]); acc[3][1] = fmaf(a3, w1, acc[3][1]); acc[3][2] = fmaf(a3, w2, acc[3][2]);
        }
        __syncthreads();
    }
#pragma unroll
    for (int i = 0; i < 4; ++i)
#pragma unroll
        for (int j = 0; j < 3; ++j)
            out[(size_t)(bm + tr * 4 + i) * XPROJ_N + tc * 3 + j] = acc[i][j];
}

// ---------------------------------------------------------------------------
// dlt = softplus(x_dbl[:, :64] @ dt_proj_w + dt_proj_b).  K=64, tiles 64x64.
// ---------------------------------------------------------------------------
__global__ __launch_bounds__(256) void dt_gemm(const float* __restrict__ xdbl,
                                               const float* __restrict__ W,
                                               const float* __restrict__ bias,
                                               float* __restrict__ out) {
    __shared__ float As[64][68];     // [q][row], +4 pad
    __shared__ float Ws[64][64];     // [q][col]
    const int tid = threadIdx.x;
    const int bm = blockIdx.x * 64, bn = blockIdx.y * 64;
#pragma unroll
    for (int l = 0; l < 4; ++l) {    // A: 64 rows x 64 q
        int i = tid + l * 256;
        int r = i >> 4, q4 = (i & 15) << 2;
        float4 v = *(const float4*)(xdbl + (size_t)(bm + r) * XPROJ_N + q4);
        As[q4 + 0][r] = v.x; As[q4 + 1][r] = v.y; As[q4 + 2][r] = v.z; As[q4 + 3][r] = v.w;
    }
#pragma unroll
    for (int l = 0; l < 4; ++l) {    // W: 64 q x 64 cols
        int i = tid + l * 256;
        int q = i >> 4, c4 = (i & 15) << 2;
        *(float4*)&Ws[q][c4] = *(const float4*)(W + (size_t)q * D_INNER + bn + c4);
    }
    __syncthreads();
    const int tx = tid & 15, ty = tid >> 4;
    float acc[4][4];
#pragma unroll
    for (int i = 0; i < 4; ++i)
#pragma unroll
        for (int j = 0; j < 4; ++j) acc[i][j] = 0.f;
#pragma unroll 16
    for (int k = 0; k < 64; ++k) {
        float a[4], w[4];
        *(float4*)a = *(const float4*)&As[k][ty * 4];
        *(float4*)w = *(const float4*)&Ws[k][tx * 4];
#pragma unroll
        for (int i = 0; i < 4; ++i)
#pragma unroll
            for (int j = 0; j < 4; ++j)
                acc[i][j] = fmaf(a[i], w[j], acc[i][j]);
    }
#pragma unroll
    for (int i = 0; i < 4; ++i) {
#pragma unroll
        for (int j = 0; j < 4; ++j) {
            float v = acc[i][j] + bias[bn + tx * 4 + j];
            float sp = fmaxf(v, 0.f) + log1pf(__expf(-fabsf(v)));
            out[(size_t)(bm + ty * 4 + i) * D_INNER + bn + tx * 4 + j] = sp;
        }
    }
}

// ---------------------------------------------------------------------------
// Chunked selective scan; carries live in the dead xc-half of xz.
//   hole(i) = (i>>11)*4096 + (i&2047)
// ---------------------------------------------------------------------------
__device__ __forceinline__ size_t hole(size_t i) {
    return (i >> 11) * 4096 + (i & 2047);
}

__global__ __launch_bounds__(256) void scan_pass1(const float* __restrict__ dlt,
                                                  const float* __restrict__ xc,
                                                  const float* __restrict__ xdbl,
                                                  const float* __restrict__ A_log,
                                                  float* __restrict__ carry) {
    __shared__ float s_B[CL][16];
    const int tid = threadIdx.x;
    const int bid = blockIdx.x;              // b*512 + c*8 + dg
    const int dg = bid & 7;
    const int c  = (bid >> 3) & (NCHUNK - 1);
    const int b  = bid >> 9;
    const int d  = dg * 256 + tid;
    const size_t rowbase = (size_t)b * SEQ + c * CL;

    float An[16];
    {
        float tmp[16];
        *(float4*)&tmp[0]  = *(const float4*)&A_log[d * 16 + 0];
        *(float4*)&tmp[4]  = *(const float4*)&A_log[d * 16 + 4];
        *(float4*)&tmp[8]  = *(const float4*)&A_log[d * 16 + 8];
        *(float4*)&tmp[12] = *(const float4*)&A_log[d * 16 + 12];
#pragma unroll
        for (int n = 0; n < 16; ++n) An[n] = -__expf(tmp[n]);
    }

#pragma unroll
    for (int p = 0; p < CL * 16 / 256; ++p) {
        int i = tid + p * 256;
        int t = i >> 4, n = i & 15;
        s_B[t][n] = xdbl[(rowbase + t) * (size_t)XPROJ_N + DT_RANK + n];
    }
    __syncthreads();

    float h[16], pA[16];
#pragma unroll
    for (int n = 0; n < 16; ++n) { h[n] = 0.f; pA[n] = 1.f; }

    const float* dtp = dlt + rowbase * D_INNER + d;
    const float* xvp = xc + rowbase * D_INNER + d;

    for (int tb = 0; tb < CL; tb += 4) {
        float dtv[4], xvv[4];
#pragma unroll
        for (int s = 0; s < 4; ++s) {
            dtv[s] = dtp[(size_t)(tb + s) * D_INNER];
            xvv[s] = xvp[(size_t)(tb + s) * D_INNER];
        }
#pragma unroll
        for (int s = 0; s < 4; ++s) {
            float Bv[16];
            *(float4*)&Bv[0]  = *(const float4*)&s_B[tb + s][0];
            *(float4*)&Bv[4]  = *(const float4*)&s_B[tb + s][4];
            *(float4*)&Bv[8]  = *(const float4*)&s_B[tb + s][8];
            *(float4*)&Bv[12] = *(const float4*)&s_B[tb + s][12];
            float du = dtv[s] * xvv[s];
#pragma unroll
            for (int n = 0; n < 16; ++n) {
                float dA = __expf(dtv[s] * An[n]);
                pA[n] *= dA;
                h[n] = fmaf(dA, h[n], du * Bv[n]);
            }
        }
    }

    size_t ci = (((size_t)b * NCHUNK + c) * D_INNER + d) * 16;
    float* pp = carry + hole(ci);
    float* hp = carry + hole(ci + ((size_t)1 << 22));
    *(float4*)&pp[0]  = *(float4*)&pA[0];  *(float4*)&pp[4]  = *(float4*)&pA[4];
    *(float4*)&pp[8]  = *(float4*)&pA[8];  *(float4*)&pp[12] = *(float4*)&pA[12];
    *(float4*)&hp[0]  = *(float4*)&h[0];   *(float4*)&hp[4]  = *(float4*)&h[4];
    *(float4*)&hp[8]  = *(float4*)&h[8];   *(float4*)&hp[12] = *(float4*)&h[12];
}

__global__ __launch_bounds__(256) void scan_pass2(float* __restrict__ carry) {
    int idx = blockIdx.x * 256 + threadIdx.x;        // over B*D*16 = 65536
    int n = idx & 15;
    int d = (idx >> 4) & (D_INNER - 1);
    int b = idx >> 15;
    float prev = 0.f;
    for (int c = 0; c < NCHUNK; ++c) {
        size_t ci = (((size_t)b * NCHUNK + c) * D_INNER + d) * 16 + n;
        size_t op = hole(ci);
        size_t oh = op + (size_t)2048 * 4096;
        float p = carry[op];
        float e = carry[oh];
        carry[oh] = prev;
        prev = fmaf(p, prev, e);
    }
}

// pass 3: re-run chunk with true h_in; y = <h,C> + xv*D; gate; write BF16.
__global__ __launch_bounds__(256) void scan_pass3(const float* __restrict__ dlt,
                                                  const float* __restrict__ xc,
                                                  const float* __restrict__ xdbl,
                                                  const float* __restrict__ xz,
                                                  const float* __restrict__ A_log,
                                                  const float* __restrict__ Dvec,
                                                  const float* __restrict__ carry,
                                                  uint16_t* __restrict__ ygb) {
    __shared__ float s_B[CL][16];
    __shared__ float s_C[CL][16];
    const int tid = threadIdx.x;
    const int bid = blockIdx.x;
    const int dg = bid & 7;
    const int c  = (bid >> 3) & (NCHUNK - 1);
    const int b  = bid >> 9;
    const int d  = dg * 256 + tid;
    const size_t rowbase = (size_t)b * SEQ + c * CL;

    float An[16];
    {
        float tmp[16];
        *(float4*)&tmp[0]  = *(const float4*)&A_log[d * 16 + 0];
        *(float4*)&tmp[4]  = *(const float4*)&A_log[d * 16 + 4];
        *(float4*)&tmp[8]  = *(const float4*)&A_log[d * 16 + 8];
        *(float4*)&tmp[12] = *(const float4*)&A_log[d * 16 + 12];
#pragma unroll
        for (int n = 0; n < 16; ++n) An[n] = -__expf(tmp[n]);
    }
    const float Dd = Dvec[d];

#pragma unroll
    for (int p = 0; p < CL * 32 / 256; ++p) {
        int i = tid + p * 256;
        int t = i >> 5, col = i & 31;
        float v = xdbl[(rowbase + t) * (size_t)XPROJ_N + DT_RANK + col];
        if (col < 16) s_B[t][col] = v;
        else          s_C[t][col - 16] = v;
    }
    __syncthreads();

    float h[16];
    {
        size_t ci = (((size_t)b * NCHUNK + c) * D_INNER + d) * 16;
        const float* hp = carry + hole(ci + ((size_t)1 << 22));
        *(float4*)&h[0]  = *(const float4*)&hp[0];
        *(float4*)&h[4]  = *(const float4*)&hp[4];
        *(float4*)&h[8]  = *(const float4*)&hp[8];
        *(float4*)&h[12] = *(const float4*)&hp[12];
    }

    const float* dtp = dlt + rowbase * D_INNER + d;
    const float* xvp = xc + rowbase * D_INNER + d;
    const float* zp  = xz + rowbase * (size_t)(2 * D_INNER) + D_INNER + d;
    uint16_t* yp = ygb + rowbase * D_INNER + d;

    for (int tb = 0; tb < CL; tb += 4) {
        float dtv[4], xvv[4], zv[4];
#pragma unroll
        for (int s = 0; s < 4; ++s) {
            dtv[s] = dtp[(size_t)(tb + s) * D_INNER];
            xvv[s] = xvp[(size_t)(tb + s) * D_INNER];
            zv[s]  = zp[(size_t)(tb + s) * (2 * D_INNER)];
        }
#pragma unroll
        for (int s = 0; s < 4; ++s) {
            float Bv[16], Cv[16];
            *(float4*)&Bv[0]  = *(const float4*)&s_B[tb + s][0];
            *(float4*)&Bv[4]  = *(const float4*)&s_B[tb + s][4];
            *(float4*)&Bv[8]  = *(const float4*)&s_B[tb + s][8];
            *(float4*)&Bv[12] = *(const float4*)&s_B[tb + s][12];
            *(float4*)&Cv[0]  = *(const float4*)&s_C[tb + s][0];
            *(float4*)&Cv[4]  = *(const float4*)&s_C[tb + s][4];
            *(float4*)&Cv[8]  = *(const float4*)&s_C[tb + s][8];
            *(float4*)&Cv[12] = *(const float4*)&s_C[tb + s][12];
            float du = dtv[s] * xvv[s];
            float y = 0.f;
#pragma unroll
            for (int n = 0; n < 16; ++n) {
                float dA = __expf(dtv[s] * An[n]);
                h[n] = fmaf(dA, h[n], du * Bv[n]);
                y = fmaf(h[n], Cv[n], y);
            }
            y = fmaf(xvv[s], Dd, y);
            float sz = zv[s] / (1.f + __expf(-zv[s]));
            yp[(size_t)(tb + s) * D_INNER] = f2bf(y * sz);
        }
    }
}

// ---------------------------------------------------------------------------
extern "C" void kernel_launch(void* const* d_in, const int* in_sizes, int n_in,
                              void* d_out, int out_size, void* d_ws, size_t ws_size,
                              hipStream_t stream) {
    const float* x          = (const float*)d_in[0];
    const float* in_proj_w  = (const float*)d_in[1];
    const float* conv_w     = (const float*)d_in[2];
    const float* conv_b     = (const float*)d_in[3];
    const float* x_proj_w   = (const float*)d_in[4];
    const float* dt_proj_w  = (const float*)d_in[5];
    const float* dt_proj_b  = (const float*)d_in[6];
    const float* A_log      = (const float*)d_in[7];
    const float* Dvec       = (const float*)d_in[8];
    const float* out_proj_w = (const float*)d_in[9];
    float* out = (float*)d_out;

    // f32 workspace regions
    float* xz     = (float*)d_ws;                          // 16,777,216 f (64MB)
    float* xc_act = xz + (size_t)NROW * 2 * D_INNER;       //  8,388,608 f (32MB)
    float* x_dbl  = xc_act + (size_t)NROW * D_INNER;       //    393,216 f (1.5MB)
    float* dlt    = x_dbl + (size_t)NROW * XPROJ_N;        //  8,388,608 f (32MB)
    // bf16 aliases with disjoint lifetimes:
    uint16_t* A1   = (uint16_t*)xc_act;                    // 24MB, dead before conv_silu
    uint16_t* B1T  = (uint16_t*)x_dbl;                     // 24MB, dead before xdbl_gemm
    uint16_t* ygb  = (uint16_t*)(dlt + (size_t)NROW * D_INNER);  // 16MB fresh
    uint16_t* opwT = ygb + (size_t)NROW * D_INNER;               //  4MB fresh

    // 1) split-bf16 operand prep for GEMM1
    cvt_x_split<<<(NROW * D_MODEL / 4) / 256, 256, 0, stream>>>(x, A1);
    cvt_wT_split<<<dim3(D_MODEL / 32, (2 * D_INNER) / 32), 256, 0, stream>>>(in_proj_w, B1T);
    // 2) xz = x @ in_proj_w  via bf16 MFMA, K' = 3*1024 (exact hi/lo split)
    gemm_bf16_bt<128><<<dim3(NROW / 128, (2 * D_INNER) / 128), 256, 0, stream>>>(
        A1, B1T, xz, NROW, 2 * D_INNER, 3 * D_MODEL);
    // 3) conv + silu (A1's region becomes xc_act here)
    conv_silu<<<(NROW * D_INNER) / 256, 256, 0, stream>>>(xz, conv_w, conv_b, xc_act);
    // 4) x_dbl = xc_act @ x_proj_w (clobbers head of dead B1T)
    xdbl_gemm<<<NROW / 32, 256, 0, stream>>>(xc_act, x_proj_w, x_dbl);
    // 5) dlt = softplus(x_dbl[:, :64] @ dt_proj_w + b)
    dt_gemm<<<dim3(NROW / 64, D_INNER / 64), 256, 0, stream>>>(x_dbl, dt_proj_w, dt_proj_b, dlt);
    // 6) chunked selective scan; pass3 writes y_gated directly as bf16
    scan_pass1<<<BATCH * NCHUNK * 8, 256, 0, stream>>>(dlt, xc_act, x_dbl, A_log, xz);
    scan_pass2<<<(BATCH * D_INNER * 16) / 256, 256, 0, stream>>>(xz);
    scan_pass3<<<BATCH * NCHUNK * 8, 256, 0, stream>>>(dlt, xc_act, x_dbl, xz,
                                                       A_log, Dvec, xz, ygb);
    // 7) out-projection operand prep + bf16 GEMM2 (skinny-N tile: 512 blocks)
    cvt_opwT<<<dim3(D_INNER / 32, D_MODEL / 32), 256, 0, stream>>>(out_proj_w, opwT);
    gemm_bf16_bt<64><<<dim3(NROW / 128, D_MODEL / 64), 256, 0, stream>>>(
        ygb, opwT, out, NROW, D_MODEL, D_INNER);
}

// Round 6
// 459.681 us; speedup vs baseline: 1.0414x; 1.0414x over previous
//
#include <hip/hip_runtime.h>
#include <hip/hip_bf16.h>
#include <stdint.h>

#define D_MODEL 1024
#define D_STATE 16
#define D_CONV 4
#define D_INNER 2048
#define DT_RANK 64
#define BATCH 2
#define SEQ 2048
#define NROW (BATCH * SEQ)          // 4096
#define XPROJ_N (DT_RANK + 2 * D_STATE)  // 96
#define NCHUNK 64                   // time chunks for scan decomposition
#define CL 32                       // SEQ / NCHUNK

typedef __bf16 bf16x8 __attribute__((ext_vector_type(8)));
typedef float  f32x4  __attribute__((ext_vector_type(4)));

// RNE f32 -> bf16 (bit trick; inputs are tame, no NaN handling needed)
__device__ __forceinline__ uint16_t f2bf(float f) {
    uint32_t u = __float_as_uint(f);
    u += 0x7FFFu + ((u >> 16) & 1u);
    return (uint16_t)(u >> 16);
}
__device__ __forceinline__ float bf2f(uint16_t h) {
    return __uint_as_float((uint32_t)h << 16);
}

#define GLOAD_LDS(g, l) __builtin_amdgcn_global_load_lds(                      \
    (const __attribute__((address_space(1))) void*)(g),                        \
    (__attribute__((address_space(3))) void*)(l), 16, 0, 0)

// ---------------------------------------------------------------------------
// bf16 MFMA GEMM, m97 structure: C(MxN,f32) = A(MxK,bf16) @ B(KxN) with B
// given TRANSPOSED (BT is N x K). 128xBN tile, BK=32, 4 waves.
//   BN=128: 2x2 waves, wave tile 64x64 (4x4 frags)
//   BN=64 : 4x1 waves, wave tile 32x64 (2x4 frags)  -- for skinny N
// Plain blockIdx mapping (bm = x, bn = y): with bm-fast linear dispatch each
// XCD gets bm-tiles = x (mod 8) -> its A-panels (3 MB) stay L2-resident and
// B-panels stream with immediate reuse. [R5 measured: custom XCD swizzle
// regressed FETCH 125->307 MB -- do not re-add.]
// ---------------------------------------------------------------------------
template <int BN>
__global__ __launch_bounds__(256) void gemm_bf16_bt(const uint16_t* __restrict__ A,
                                                    const uint16_t* __restrict__ BT,
                                                    float* __restrict__ C,
                                                    int M, int N, int K) {
    constexpr int WROWS = (BN == 128) ? 64 : 32;    // rows per wave
    constexpr int MF = WROWS / 16;                  // m-frags per wave
    __shared__ uint16_t sA[128 * 32];               // [row][k], 64B rows
    __shared__ uint16_t sB[BN * 32];                // [n][k]
    const int tid  = threadIdx.x;
    const int wave = tid >> 6;          // 0..3
    const int lane = tid & 63;
    const int wm = (BN == 128) ? (wave >> 1) : wave;
    const int wn = (BN == 128) ? (wave & 1) : 0;
    const int bm = blockIdx.x * 128;
    const int bn = blockIdx.y * BN;

    // staging: lane covers 16B: row = seg_base + (lane>>2), col = (lane&3)*8
    const int lrow = lane >> 2;
    const int lcol = (lane & 3) * 8;
    const uint16_t* gA0 = A + (size_t)(bm + wave * 32 + lrow) * K + lcol;
    const uint16_t* gA1 = gA0 + (size_t)16 * K;
    uint16_t* lA0 = sA + (wave * 2 + 0) * 512;
    uint16_t* lA1 = sA + (wave * 2 + 1) * 512;
    const uint16_t* gB0;
    const uint16_t* gB1 = nullptr;
    uint16_t* lB0;
    uint16_t* lB1 = nullptr;
    if constexpr (BN == 128) {
        gB0 = BT + (size_t)(bn + wave * 32 + lrow) * K + lcol;
        gB1 = gB0 + (size_t)16 * K;
        lB0 = sB + (wave * 2 + 0) * 512;
        lB1 = sB + (wave * 2 + 1) * 512;
    } else {
        gB0 = BT + (size_t)(bn + wave * 16 + lrow) * K + lcol;
        lB0 = sB + wave * 512;
    }

    const int fr = lane & 15;           // frag row (A: m-row, B: n-col)
    const int fg = lane >> 4;           // frag k-group

    f32x4 acc[MF][4] = {};

    for (int k0 = 0; k0 < K; k0 += 32) {
        GLOAD_LDS(gA0 + k0, lA0);
        GLOAD_LDS(gA1 + k0, lA1);
        GLOAD_LDS(gB0 + k0, lB0);
        if constexpr (BN == 128) GLOAD_LDS(gB1 + k0, lB1);
        __syncthreads();                 // drains vmcnt before barrier

        bf16x8 af[MF], bfr[4];
#pragma unroll
        for (int m = 0; m < MF; ++m)
            af[m] = *(const bf16x8*)&sA[(wm * WROWS + m * 16 + fr) * 32 + fg * 8];
#pragma unroll
        for (int n = 0; n < 4; ++n)
            bfr[n] = *(const bf16x8*)&sB[(wn * 64 + n * 16 + fr) * 32 + fg * 8];
#pragma unroll
        for (int m = 0; m < MF; ++m)
#pragma unroll
            for (int n = 0; n < 4; ++n)
                acc[m][n] = __builtin_amdgcn_mfma_f32_16x16x32_bf16(
                    af[m], bfr[n], acc[m][n], 0, 0, 0);
        __syncthreads();
    }

    // C/D layout: col = lane&15, row = (lane>>4)*4 + reg  [m89-verified]
#pragma unroll
    for (int m = 0; m < MF; ++m)
#pragma unroll
        for (int n = 0; n < 4; ++n) {
            const int col = bn + wn * 64 + n * 16 + fr;
#pragma unroll
            for (int r = 0; r < 4; ++r) {
                const int row = bm + wm * WROWS + m * 16 + fg * 4 + r;
                C[(size_t)row * N + col] = acc[m][n][r];
            }
        }
}

// ---------------------------------------------------------------------------
// x (4096x1024 f32) -> A' (4096x3072 bf16) = [hi | lo | hi]
// ---------------------------------------------------------------------------
__global__ __launch_bounds__(256) void cvt_x_split(const float* __restrict__ x,
                                                   uint16_t* __restrict__ a1) {
    const int i = blockIdx.x * 256 + threadIdx.x;    // float4 index
    const int m = i >> 8;                            // 256 float4 per row
    const int c = (i & 255) << 2;
    const float4 v = ((const float4*)x)[i];
    uint16_t h[4], l[4];
    const float vf[4] = {v.x, v.y, v.z, v.w};
#pragma unroll
    for (int j = 0; j < 4; ++j) {
        h[j] = f2bf(vf[j]);
        l[j] = f2bf(vf[j] - bf2f(h[j]));
    }
    const size_t base = (size_t)m * 3072 + c;
    *(ushort4*)&a1[base]        = *(ushort4*)h;
    *(ushort4*)&a1[base + 1024] = *(ushort4*)l;
    *(ushort4*)&a1[base + 2048] = *(ushort4*)h;
}

// ---------------------------------------------------------------------------
// in_proj_w (1024x4096 f32) -> B'T (4096x3072 bf16): B'T[n][*] = [hi | hi | lo]
// of column n. 32x32 LDS transpose tiles.
// ---------------------------------------------------------------------------
__global__ __launch_bounds__(256) void cvt_wT_split(const float* __restrict__ w,
                                                    uint16_t* __restrict__ bt) {
    __shared__ float s[32][33];
    const int tid = threadIdx.x;
    const int k0 = blockIdx.x * 32;   // source row tile (K dim)
    const int n0 = blockIdx.y * 32;   // source col tile (N dim)
#pragma unroll
    for (int p = 0; p < 4; ++p) {
        int lin = tid + p * 256;
        int i = lin >> 5, j = lin & 31;
        s[i][j] = w[(size_t)(k0 + i) * 4096 + n0 + j];
    }
    __syncthreads();
    const int r = tid >> 3, c4 = (tid & 7) * 4;      // r: n-local, c4: k-local
    uint16_t h[4], l[4];
#pragma unroll
    for (int j = 0; j < 4; ++j) {
        float v = s[c4 + j][r];
        h[j] = f2bf(v);
        l[j] = f2bf(v - bf2f(h[j]));
    }
    const size_t base = (size_t)(n0 + r) * 3072 + k0 + c4;
    *(ushort4*)&bt[base]        = *(ushort4*)h;
    *(ushort4*)&bt[base + 1024] = *(ushort4*)h;
    *(ushort4*)&bt[base + 2048] = *(ushort4*)l;
}

// ---------------------------------------------------------------------------
// out_proj_w (2048x1024 f32) -> opwT (1024x2048 bf16), plain hi.
// ---------------------------------------------------------------------------
__global__ __launch_bounds__(256) void cvt_opwT(const float* __restrict__ w,
                                                uint16_t* __restrict__ bt) {
    __shared__ float s[32][33];
    const int tid = threadIdx.x;
    const int k0 = blockIdx.x * 32;   // source row tile (K=2048 dim)
    const int n0 = blockIdx.y * 32;   // source col tile (N=1024 dim)
#pragma unroll
    for (int p = 0; p < 4; ++p) {
        int lin = tid + p * 256;
        int i = lin >> 5, j = lin & 31;
        s[i][j] = w[(size_t)(k0 + i) * 1024 + n0 + j];
    }
    __syncthreads();
    const int r = tid >> 3, c4 = (tid & 7) * 4;
    uint16_t h[4];
#pragma unroll
    for (int j = 0; j < 4; ++j) h[j] = f2bf(s[c4 + j][r]);
    *(ushort4*)&bt[(size_t)(n0 + r) * 2048 + k0 + c4] = *(ushort4*)h;
}

// ---------------------------------------------------------------------------
// Causal depthwise conv (D_CONV=4) + bias + SiLU.
// ---------------------------------------------------------------------------
__global__ __launch_bounds__(256) void conv_silu(const float* __restrict__ xz,
                                                 const float* __restrict__ conv_w,
                                                 const float* __restrict__ conv_b,
                                                 float* __restrict__ xc_act) {
    int idx = blockIdx.x * 256 + threadIdx.x;       // over NROW*D_INNER
    int d = idx & (D_INNER - 1);
    int r = idx >> 11;                               // b*SEQ + t
    int t = r & (SEQ - 1);
    float acc = conv_b[d];
#pragma unroll
    for (int k = 0; k < D_CONV; ++k) {
        int tt = t + k - (D_CONV - 1);
        if (tt >= 0)
            acc = fmaf(xz[(size_t)(r + k - (D_CONV - 1)) * (2 * D_INNER) + d],
                       conv_w[d * D_CONV + k], acc);
    }
    float s = acc / (1.f + __expf(-acc));            // silu
    xc_act[(size_t)r * D_INNER + d] = s;
}

// ---------------------------------------------------------------------------
// x_dbl = xc_act (NROW x D_INNER) @ x_proj_w (D_INNER x 96). BM=32, full N=96.
// ---------------------------------------------------------------------------
__global__ __launch_bounds__(256) void xdbl_gemm(const float* __restrict__ A,
                                                 const float* __restrict__ W,
                                                 float* __restrict__ out) {
    __shared__ float As[32][132];    // [row][k], +4 pad
    __shared__ float Ws[128][96];    // [k][col]
    const int tid = threadIdx.x;
    const int bm = blockIdx.x * 32;
    const int tc = tid & 31;         // cols tc*3 .. +2
    const int tr = tid >> 5;         // rows tr*4 .. +3
    float acc[4][3];
#pragma unroll
    for (int i = 0; i < 4; ++i)
#pragma unroll
        for (int j = 0; j < 3; ++j) acc[i][j] = 0.f;

    for (int k0 = 0; k0 < D_INNER; k0 += 128) {
#pragma unroll
        for (int l = 0; l < 4; ++l) {                 // A tile 32x128
            int i = tid + l * 256;
            int r = i >> 5, c4 = (i & 31) << 2;
            *(float4*)&As[r][c4] = *(const float4*)(A + (size_t)(bm + r) * D_INNER + k0 + c4);
        }
#pragma unroll
        for (int l = 0; l < 12; ++l) {                // W tile 128x96
            int i = tid + l * 256;
            int r = i / 24, c4 = (i % 24) << 2;
            *(float4*)&Ws[r][c4] = *(const float4*)(W + (size_t)(k0 + r) * XPROJ_N + c4);
        }
        __syncthreads();
#pragma unroll 8
        for (int k = 0; k < 128; ++k) {
            float a0 = As[tr * 4 + 0][k], a1 = As[tr * 4 + 1][k];
            float a2 = As[tr * 4 + 2][k], a3 = As[tr * 4 + 3][k];
            float w0 = Ws[k][tc * 3 + 0], w1 = Ws[k][tc * 3 + 1], w2 = Ws[k][tc * 3 + 2];
            acc[0][0] = fmaf(a0, w0, acc[0][0]); acc[0][1] = fmaf(a0, w1, acc[0][1]); acc[0][2] = fmaf(a0, w2, acc[0][2]);
            acc[1][0] = fmaf(a1, w0, acc[1][0]); acc[1][1] = fmaf(a1, w1, acc[1][1]); acc[1][2] = fmaf(a1, w2, acc[1][2]);
            acc[2][0] = fmaf(a2, w0, acc[2][0]); acc[2][1] = fmaf(a2, w1, acc[2][1]); acc[2][2] = fmaf(a2, w2, acc[2][2]);
            acc[3][0] = fmaf(a3, w0, acc[3][0]); acc[3][1] = fmaf(a3, w1, acc[3][1]); acc[3][2] = fmaf(a3, w2, acc[3][2]);
        }
        __syncthreads();
    }
#pragma unroll
    for (int i = 0; i < 4; ++i)
#pragma unroll
        for (int j = 0; j < 3; ++j)
            out[(size_t)(bm + tr * 4 + i) * XPROJ_N + tc * 3 + j] = acc[i][j];
}

// ---------------------------------------------------------------------------
// dlt = softplus(x_dbl[:, :64] @ dt_proj_w + dt_proj_b).  K=64, tiles 64x64.
// ---------------------------------------------------------------------------
__global__ __launch_bounds__(256) void dt_gemm(const float* __restrict__ xdbl,
                                               const float* __restrict__ W,
                                               const float* __restrict__ bias,
                                               float* __restrict__ out) {
    __shared__ float As[64][68];     // [q][row], +4 pad
    __shared__ float Ws[64][64];     // [q][col]
    const int tid = threadIdx.x;
    const int bm = blockIdx.x * 64, bn = blockIdx.y * 64;
#pragma unroll
    for (int l = 0; l < 4; ++l) {    // A: 64 rows x 64 q
        int i = tid + l * 256;
        int r = i >> 4, q4 = (i & 15) << 2;
        float4 v = *(const float4*)(xdbl + (size_t)(bm + r) * XPROJ_N + q4);
        As[q4 + 0][r] = v.x; As[q4 + 1][r] = v.y; As[q4 + 2][r] = v.z; As[q4 + 3][r] = v.w;
    }
#pragma unroll
    for (int l = 0; l < 4; ++l) {    // W: 64 q x 64 cols
        int i = tid + l * 256;
        int q = i >> 4, c4 = (i & 15) << 2;
        *(float4*)&Ws[q][c4] = *(const float4*)(W + (size_t)q * D_INNER + bn + c4);
    }
    __syncthreads();
    const int tx = tid & 15, ty = tid >> 4;
    float acc[4][4];
#pragma unroll
    for (int i = 0; i < 4; ++i)
#pragma unroll
        for (int j = 0; j < 4; ++j) acc[i][j] = 0.f;
#pragma unroll 16
    for (int k = 0; k < 64; ++k) {
        float a[4], w[4];
        *(float4*)a = *(const float4*)&As[k][ty * 4];
        *(float4*)w = *(const float4*)&Ws[k][tx * 4];
#pragma unroll
        for (int i = 0; i < 4; ++i)
#pragma unroll
            for (int j = 0; j < 4; ++j)
                acc[i][j] = fmaf(a[i], w[j], acc[i][j]);
    }
#pragma unroll
    for (int i = 0; i < 4; ++i) {
#pragma unroll
        for (int j = 0; j < 4; ++j) {
            float v = acc[i][j] + bias[bn + tx * 4 + j];
            float sp = fmaxf(v, 0.f) + log1pf(__expf(-fabsf(v)));
            out[(size_t)(bm + ty * 4 + i) * D_INNER + bn + tx * 4 + j] = sp;
        }
    }
}

// ---------------------------------------------------------------------------
// Chunked selective scan; carries live in the dead xc-half of xz.
//   hole(i) = (i>>11)*4096 + (i&2047)
// ---------------------------------------------------------------------------
__device__ __forceinline__ size_t hole(size_t i) {
    return (i >> 11) * 4096 + (i & 2047);
}

__global__ __launch_bounds__(256) void scan_pass1(const float* __restrict__ dlt,
                                                  const float* __restrict__ xc,
                                                  const float* __restrict__ xdbl,
                                                  const float* __restrict__ A_log,
                                                  float* __restrict__ carry) {
    __shared__ float s_B[CL][16];
    const int tid = threadIdx.x;
    const int bid = blockIdx.x;              // b*512 + c*8 + dg
    const int dg = bid & 7;
    const int c  = (bid >> 3) & (NCHUNK - 1);
    const int b  = bid >> 9;
    const int d  = dg * 256 + tid;
    const size_t rowbase = (size_t)b * SEQ + c * CL;

    float An[16];
    {
        float tmp[16];
        *(float4*)&tmp[0]  = *(const float4*)&A_log[d * 16 + 0];
        *(float4*)&tmp[4]  = *(const float4*)&A_log[d * 16 + 4];
        *(float4*)&tmp[8]  = *(const float4*)&A_log[d * 16 + 8];
        *(float4*)&tmp[12] = *(const float4*)&A_log[d * 16 + 12];
#pragma unroll
        for (int n = 0; n < 16; ++n) An[n] = -__expf(tmp[n]);
    }

#pragma unroll
    for (int p = 0; p < CL * 16 / 256; ++p) {
        int i = tid + p * 256;
        int t = i >> 4, n = i & 15;
        s_B[t][n] = xdbl[(rowbase + t) * (size_t)XPROJ_N + DT_RANK + n];
    }
    __syncthreads();

    float h[16], pA[16];
#pragma unroll
    for (int n = 0; n < 16; ++n) { h[n] = 0.f; pA[n] = 1.f; }

    const float* dtp = dlt + rowbase * D_INNER + d;
    const float* xvp = xc + rowbase * D_INNER + d;

    for (int tb = 0; tb < CL; tb += 4) {
        float dtv[4], xvv[4];
#pragma unroll
        for (int s = 0; s < 4; ++s) {
            dtv[s] = dtp[(size_t)(tb + s) * D_INNER];
            xvv[s] = xvp[(size_t)(tb + s) * D_INNER];
        }
#pragma unroll
        for (int s = 0; s < 4; ++s) {
            float Bv[16];
            *(float4*)&Bv[0]  = *(const float4*)&s_B[tb + s][0];
            *(float4*)&Bv[4]  = *(const float4*)&s_B[tb + s][4];
            *(float4*)&Bv[8]  = *(const float4*)&s_B[tb + s][8];
            *(float4*)&Bv[12] = *(const float4*)&s_B[tb + s][12];
            float du = dtv[s] * xvv[s];
#pragma unroll
            for (int n = 0; n < 16; ++n) {
                float dA = __expf(dtv[s] * An[n]);
                pA[n] *= dA;
                h[n] = fmaf(dA, h[n], du * Bv[n]);
            }
        }
    }

    size_t ci = (((size_t)b * NCHUNK + c) * D_INNER + d) * 16;
    float* pp = carry + hole(ci);
    float* hp = carry + hole(ci + ((size_t)1 << 22));
    *(float4*)&pp[0]  = *(float4*)&pA[0];  *(float4*)&pp[4]  = *(float4*)&pA[4];
    *(float4*)&pp[8]  = *(float4*)&pA[8];  *(float4*)&pp[12] = *(float4*)&pA[12];
    *(float4*)&hp[0]  = *(float4*)&h[0];   *(float4*)&hp[4]  = *(float4*)&h[4];
    *(float4*)&hp[8]  = *(float4*)&h[8];   *(float4*)&hp[12] = *(float4*)&h[12];
}

__global__ __launch_bounds__(256) void scan_pass2(float* __restrict__ carry) {
    int idx = blockIdx.x * 256 + threadIdx.x;        // over B*D*16 = 65536
    int n = idx & 15;
    int d = (idx >> 4) & (D_INNER - 1);
    int b = idx >> 15;
    float prev = 0.f;
    for (int c = 0; c < NCHUNK; ++c) {
        size_t ci = (((size_t)b * NCHUNK + c) * D_INNER + d) * 16 + n;
        size_t op = hole(ci);
        size_t oh = op + (size_t)2048 * 4096;
        float p = carry[op];
        float e = carry[oh];
        carry[oh] = prev;
        prev = fmaf(p, prev, e);
    }
}

// pass 3: re-run chunk with true h_in; y = <h,C> + xv*D; gate; write BF16.
__global__ __launch_bounds__(256) void scan_pass3(const float* __restrict__ dlt,
                                                  const float* __restrict__ xc,
                                                  const float* __restrict__ xdbl,
                                                  const float* __restrict__ xz,
                                                  const float* __restrict__ A_log,
                                                  const float* __restrict__ Dvec,
                                                  const float* __restrict__ carry,
                                                  uint16_t* __restrict__ ygb) {
    __shared__ float s_B[CL][16];
    __shared__ float s_C[CL][16];
    const int tid = threadIdx.x;
    const int bid = blockIdx.x;
    const int dg = bid & 7;
    const int c  = (bid >> 3) & (NCHUNK - 1);
    const int b  = bid >> 9;
    const int d  = dg * 256 + tid;
    const size_t rowbase = (size_t)b * SEQ + c * CL;

    float An[16];
    {
        float tmp[16];
        *(float4*)&tmp[0]  = *(const float4*)&A_log[d * 16 + 0];
        *(float4*)&tmp[4]  = *(const float4*)&A_log[d * 16 + 4];
        *(float4*)&tmp[8]  = *(const float4*)&A_log[d * 16 + 8];
        *(float4*)&tmp[12] = *(const float4*)&A_log[d * 16 + 12];
#pragma unroll
        for (int n = 0; n < 16; ++n) An[n] = -__expf(tmp[n]);
    }
    const float Dd = Dvec[d];

#pragma unroll
    for (int p = 0; p < CL * 32 / 256; ++p) {
        int i = tid + p * 256;
        int t = i >> 5, col = i & 31;
        float v = xdbl[(rowbase + t) * (size_t)XPROJ_N + DT_RANK + col];
        if (col < 16) s_B[t][col] = v;
        else          s_C[t][col - 16] = v;
    }
    __syncthreads();

    float h[16];
    {
        size_t ci = (((size_t)b * NCHUNK + c) * D_INNER + d) * 16;
        const float* hp = carry + hole(ci + ((size_t)1 << 22));
        *(float4*)&h[0]  = *(const float4*)&hp[0];
        *(float4*)&h[4]  = *(const float4*)&hp[4];
        *(float4*)&h[8]  = *(const float4*)&hp[8];
        *(float4*)&h[12] = *(const float4*)&hp[12];
    }

    const float* dtp = dlt + rowbase * D_INNER + d;
    const float* xvp = xc + rowbase * D_INNER + d;
    const float* zp  = xz + rowbase * (size_t)(2 * D_INNER) + D_INNER + d;
    uint16_t* yp = ygb + rowbase * D_INNER + d;

    for (int tb = 0; tb < CL; tb += 4) {
        float dtv[4], xvv[4], zv[4];
#pragma unroll
        for (int s = 0; s < 4; ++s) {
            dtv[s] = dtp[(size_t)(tb + s) * D_INNER];
            xvv[s] = xvp[(size_t)(tb + s) * D_INNER];
            zv[s]  = zp[(size_t)(tb + s) * (2 * D_INNER)];
        }
#pragma unroll
        for (int s = 0; s < 4; ++s) {
            float Bv[16], Cv[16];
            *(float4*)&Bv[0]  = *(const float4*)&s_B[tb + s][0];
            *(float4*)&Bv[4]  = *(const float4*)&s_B[tb + s][4];
            *(float4*)&Bv[8]  = *(const float4*)&s_B[tb + s][8];
            *(float4*)&Bv[12] = *(const float4*)&s_B[tb + s][12];
            *(float4*)&Cv[0]  = *(const float4*)&s_C[tb + s][0];
            *(float4*)&Cv[4]  = *(const float4*)&s_C[tb + s][4];
            *(float4*)&Cv[8]  = *(const float4*)&s_C[tb + s][8];
            *(float4*)&Cv[12] = *(const float4*)&s_C[tb + s][12];
            float du = dtv[s] * xvv[s];
            float y = 0.f;
#pragma unroll
            for (int n = 0; n < 16; ++n) {
                float dA = __expf(dtv[s] * An[n]);
                h[n] = fmaf(dA, h[n], du * Bv[n]);
                y = fmaf(h[n], Cv[n], y);
            }
            y = fmaf(xvv[s], Dd, y);
            float sz = zv[s] / (1.f + __expf(-zv[s]));
            yp[(size_t)(tb + s) * D_INNER] = f2bf(y * sz);
        }
    }
}

// ---------------------------------------------------------------------------
extern "C" void kernel_launch(void* const* d_in, const int* in_sizes, int n_in,
                              void* d_out, int out_size, void* d_ws, size_t ws_size,
                              hipStream_t stream) {
    const float* x          = (const float*)d_in[0];
    const float* in_proj_w  = (const float*)d_in[1];
    const float* conv_w     = (const float*)d_in[2];
    const float* conv_b     = (const float*)d_in[3];
    const float* x_proj_w   = (const float*)d_in[4];
    const float* dt_proj_w  = (const float*)d_in[5];
    const float* dt_proj_b  = (const float*)d_in[6];
    const float* A_log      = (const float*)d_in[7];
    const float* Dvec       = (const float*)d_in[8];
    const float* out_proj_w = (const float*)d_in[9];
    float* out = (float*)d_out;

    // f32 workspace regions
    float* xz     = (float*)d_ws;                          // 16,777,216 f (64MB)
    float* xc_act = xz + (size_t)NROW * 2 * D_INNER;       //  8,388,608 f (32MB)
    float* x_dbl  = xc_act + (size_t)NROW * D_INNER;       //    393,216 f (1.5MB)
    float* dlt    = x_dbl + (size_t)NROW * XPROJ_N;        //  8,388,608 f (32MB)
    // bf16 aliases with disjoint lifetimes:
    uint16_t* A1   = (uint16_t*)xc_act;                    // 24MB, dead before conv_silu
    uint16_t* B1T  = (uint16_t*)x_dbl;                     // 24MB, dead before xdbl_gemm
    uint16_t* ygb  = (uint16_t*)(dlt + (size_t)NROW * D_INNER);  // 16MB fresh
    uint16_t* opwT = ygb + (size_t)NROW * D_INNER;               //  4MB fresh

    // 1) split-bf16 operand prep for GEMM1
    cvt_x_split<<<(NROW * D_MODEL / 4) / 256, 256, 0, stream>>>(x, A1);
    cvt_wT_split<<<dim3(D_MODEL / 32, (2 * D_INNER) / 32), 256, 0, stream>>>(in_proj_w, B1T);
    // 2) xz = x @ in_proj_w  via bf16 MFMA, K' = 3*1024 (exact hi/lo split)
    gemm_bf16_bt<128><<<dim3(NROW / 128, (2 * D_INNER) / 128), 256, 0, stream>>>(
        A1, B1T, xz, NROW, 2 * D_INNER, 3 * D_MODEL);
    // 3) conv + silu (A1's region becomes xc_act here)
    conv_silu<<<(NROW * D_INNER) / 256, 256, 0, stream>>>(xz, conv_w, conv_b, xc_act);
    // 4) x_dbl = xc_act @ x_proj_w (clobbers head of dead B1T)
    xdbl_gemm<<<NROW / 32, 256, 0, stream>>>(xc_act, x_proj_w, x_dbl);
    // 5) dlt = softplus(x_dbl[:, :64] @ dt_proj_w + b)
    dt_gemm<<<dim3(NROW / 64, D_INNER / 64), 256, 0, stream>>>(x_dbl, dt_proj_w, dt_proj_b, dlt);
    // 6) chunked selective scan; pass3 writes y_gated directly as bf16
    scan_pass1<<<BATCH * NCHUNK * 8, 256, 0, stream>>>(dlt, xc_act, x_dbl, A_log, xz);
    scan_pass2<<<(BATCH * D_INNER * 16) / 256, 256, 0, stream>>>(xz);
    scan_pass3<<<BATCH * NCHUNK * 8, 256, 0, stream>>>(dlt, xc_act, x_dbl, xz,
                                                       A_log, Dvec, xz, ygb);
    // 7) out-projection operand prep + bf16 GEMM2 (skinny-N tile: 512 blocks)
    cvt_opwT<<<dim3(D_INNER / 32, D_MODEL / 32), 256, 0, stream>>>(out_proj_w, opwT);
    gemm_bf16_bt<64><<<dim3(NROW / 128, D_MODEL / 64), 256, 0, stream>>>(
        ygb, opwT, out, NROW, D_MODEL, D_INNER);
}

// Round 7
// 423.190 us; speedup vs baseline: 1.1312x; 1.0862x over previous
//
#include <hip/hip_runtime.h>
#include <hip/hip_bf16.h>
#include <stdint.h>

#define D_MODEL 1024
#define D_STATE 16
#define D_CONV 4
#define D_INNER 2048
#define DT_RANK 64
#define BATCH 2
#define SEQ 2048
#define NROW (BATCH * SEQ)          // 4096
#define XPROJ_N (DT_RANK + 2 * D_STATE)  // 96
#define NCHUNK 64                   // time chunks for scan decomposition
#define CL 32                       // SEQ / NCHUNK

typedef __bf16 bf16x8 __attribute__((ext_vector_type(8)));
typedef float  f32x4  __attribute__((ext_vector_type(4)));

// RNE f32 -> bf16 (bit trick; inputs are tame, no NaN handling needed)
__device__ __forceinline__ uint16_t f2bf(float f) {
    uint32_t u = __float_as_uint(f);
    u += 0x7FFFu + ((u >> 16) & 1u);
    return (uint16_t)(u >> 16);
}
__device__ __forceinline__ float bf2f(uint16_t h) {
    return __uint_as_float((uint32_t)h << 16);
}

#define GLOAD_LDS(g, l) __builtin_amdgcn_global_load_lds(                      \
    (const __attribute__((address_space(1))) void*)(g),                        \
    (__attribute__((address_space(3))) void*)(l), 16, 0, 0)

// ===========================================================================
// 256x256 8-phase bf16 GEMM (T2 swizzle + T3/T4 counted vmcnt + T5 setprio).
// C(MxN,f32) = A(MxK,bf16) @ BT(NxK,bf16)^T.  Grid (M/256, N/256), 512 thr.
// LDS 128 KB: buf{0,1} x {A,B} x half{0,1} x 8192 elems (16 KB each).
// Swizzle st_16x32 in elems: e ^= ((e>>8)&1)<<4  (involution), applied as
// pre-swizzled GLOBAL source + swizzled ds_read (gload_lds dest stays linear).
// Stage stream (iter i, tiles T0=2i buf0, T1=2i+1 buf1):
//   ph1:A0(T1) ph2:A1(T1) ph3:B0(T0+2) ph4:B1(T0+2)+vmcnt(4)
//   ph5:A0(T0+2) ph6:A1(T0+2) ph7:B0(T1+2) ph8:B1(T1+2)+vmcnt(4)
// Ledger: FIFO vmcnt(4) at ph4 retires {B0,B1(T1) [prev ph7/8], A0,A1(T1)}
// => tile T1 resident at ph5; at ph8 retires all of T0+2 => resident at ph1.
// ===========================================================================
#define LDA8(BUF, MH) do {                                                     \
  _Pragma("unroll") for (int m_ = 0; m_ < 4; ++m_)                             \
    _Pragma("unroll") for (int ks_ = 0; ks_ < 2; ++ks_) {                      \
      int e_ = (((MH)*64 + m_*16 + fr) << 6) + ks_*32 + fg*8;                  \
      e_ ^= ((e_ >> 8) & 1) << 4;                                              \
      a[m_][ks_] = *(const bf16x8*)&lds[(BUF)*32768 + wm*8192 + e_];           \
    }                                                                          \
} while (0)

#define LDB4(BUF, NH) do {                                                     \
  _Pragma("unroll") for (int n_ = 0; n_ < 2; ++n_)                             \
    _Pragma("unroll") for (int ks_ = 0; ks_ < 2; ++ks_) {                      \
      int e_ = ((((wn & 1)*64) + (NH)*32 + n_*16 + fr) << 6) + ks_*32 + fg*8;  \
      e_ ^= ((e_ >> 8) & 1) << 4;                                              \
      bb[NH][n_][ks_] = *(const bf16x8*)&lds[(BUF)*32768 + 16384 +             \
                                             (wn >> 1)*8192 + e_];             \
    }                                                                          \
} while (0)

#define MFMA16(MH, NH) do {                                                    \
  __builtin_amdgcn_s_setprio(1);                                               \
  _Pragma("unroll") for (int m_ = 0; m_ < 4; ++m_)                             \
    _Pragma("unroll") for (int n_ = 0; n_ < 2; ++n_)                           \
      _Pragma("unroll") for (int ks_ = 0; ks_ < 2; ++ks_)                      \
        acc[(MH)*4 + m_][(NH)*2 + n_] = __builtin_amdgcn_mfma_f32_16x16x32_bf16( \
            a[m_][ks_], bb[NH][n_][ks_], acc[(MH)*4 + m_][(NH)*2 + n_], 0, 0, 0); \
  __builtin_amdgcn_s_setprio(0);                                               \
} while (0)

#define STAGE(MAT, HALF, T) do {                                               \
  if ((T) < NT) {                                                              \
    const uint16_t* s0_ = ((MAT) ? Bs0 : As0) + (size_t)(HALF)*128*K + (size_t)(T)*64; \
    const uint16_t* s1_ = ((MAT) ? Bs1 : As1) + (size_t)(HALF)*128*K + (size_t)(T)*64; \
    uint16_t* d_ = lds + (((T) & 1)*32768 + (MAT)*16384 + (HALF)*8192 + wave*512); \
    GLOAD_LDS(s0_, d_);                                                        \
    GLOAD_LDS(s1_, d_ + 4096);                                                 \
  }                                                                            \
} while (0)

#define BAR()  __builtin_amdgcn_s_barrier()
#define LGKM0() do { asm volatile("s_waitcnt lgkmcnt(0)" ::: "memory");        \
                     __builtin_amdgcn_sched_barrier(0); } while (0)
#define VM4()  do { asm volatile("s_waitcnt vmcnt(4)" ::: "memory");           \
                    __builtin_amdgcn_sched_barrier(0); } while (0)

__global__ __launch_bounds__(512, 2) void gemm256_8p(const uint16_t* __restrict__ A,
                                                     const uint16_t* __restrict__ BT,
                                                     float* __restrict__ C,
                                                     int M, int N, int K) {
    extern __shared__ uint16_t lds[];           // 131072 bytes
    const int tid  = threadIdx.x;
    const int wave = tid >> 6, lane = tid & 63;
    const int wm = wave >> 2, wn = wave & 3;    // 2M x 4N wave grid
    const int fr = lane & 15, fg = lane >> 4;
    const int bm = blockIdx.x * 256, bn = blockIdx.y * 256;
    const int NT = K >> 6;                      // number of K-tiles (BK=64)
    const int NIT = NT >> 1;

    // staging source (pre-swizzled global): round p covers LDS elems
    // o = p*4096 + wave*512 + lane*8 ; logical le = o ^ ((lane>>5 & 1)<<4)
    const int srow = wave * 8 + (lane >> 3);              // p=0 row; p=1: +64
    const int skcol = ((lane & 7) * 8) ^ (((lane >> 5) & 1) << 4);
    const uint16_t* As0 = A  + (size_t)(bm + srow) * K + skcol;
    const uint16_t* As1 = A  + (size_t)(bm + srow + 64) * K + skcol;
    const uint16_t* Bs0 = BT + (size_t)(bn + srow) * K + skcol;
    const uint16_t* Bs1 = BT + (size_t)(bn + srow + 64) * K + skcol;

    f32x4 acc[8][4] = {};
    bf16x8 a[4][2];
    bf16x8 bb[2][2][2];

    // prologue: tile0 (all 4 halves) + tile1 B halves; drain to 4 outstanding
    STAGE(0, 0, 0); STAGE(0, 1, 0); STAGE(1, 0, 0); STAGE(1, 1, 0);
    STAGE(1, 0, 1); STAGE(1, 1, 1);
    VM4(); BAR();

    for (int i = 0; i < NIT; ++i) {
        const int T0 = 2 * i, T1 = 2 * i + 1;
        // ---- K-step T0 (buf0) ----
        LDA8(0, 0); LDB4(0, 0); STAGE(0, 0, T1);
        BAR(); LGKM0(); MFMA16(0, 0); BAR();
        LDB4(0, 1);             STAGE(0, 1, T1);
        BAR(); LGKM0(); MFMA16(0, 1); BAR();
        LDA8(0, 1);             STAGE(1, 0, T0 + 2);
        BAR(); LGKM0(); MFMA16(1, 0); BAR();
                                STAGE(1, 1, T0 + 2);
        VM4();
        BAR(); LGKM0(); MFMA16(1, 1); BAR();
        // ---- K-step T1 (buf1) ----
        LDA8(1, 0); LDB4(1, 0); STAGE(0, 0, T0 + 2);
        BAR(); LGKM0(); MFMA16(0, 0); BAR();
        LDB4(1, 1);             STAGE(0, 1, T0 + 2);
        BAR(); LGKM0(); MFMA16(0, 1); BAR();
        LDA8(1, 1);             STAGE(1, 0, T1 + 2);
        BAR(); LGKM0(); MFMA16(1, 0); BAR();
                                STAGE(1, 1, T1 + 2);
        VM4();
        BAR(); LGKM0(); MFMA16(1, 1); BAR();
    }

    // epilogue: C/D layout col = lane&15, row = (lane>>4)*4 + reg
    const int crow0 = bm + wm * 128 + fg * 4;
    const int ccol0 = bn + wn * 64 + fr;
#pragma unroll
    for (int mp = 0; mp < 8; ++mp)
#pragma unroll
        for (int np = 0; np < 4; ++np)
#pragma unroll
            for (int r = 0; r < 4; ++r)
                C[(size_t)(crow0 + mp * 16 + r) * N + ccol0 + np * 16] = acc[mp][np][r];
}

// ---------------------------------------------------------------------------
// m97-structure bf16 GEMM for skinny N (GEMM2). BN=64: 4x1 waves, 32x64/wave.
// ---------------------------------------------------------------------------
template <int BN>
__global__ __launch_bounds__(256) void gemm_bf16_bt(const uint16_t* __restrict__ A,
                                                    const uint16_t* __restrict__ BT,
                                                    float* __restrict__ C,
                                                    int M, int N, int K) {
    constexpr int WROWS = (BN == 128) ? 64 : 32;
    constexpr int MF = WROWS / 16;
    __shared__ uint16_t sA[128 * 32];
    __shared__ uint16_t sB[BN * 32];
    const int tid  = threadIdx.x;
    const int wave = tid >> 6;
    const int lane = tid & 63;
    const int wm = (BN == 128) ? (wave >> 1) : wave;
    const int wn = (BN == 128) ? (wave & 1) : 0;
    const int bm = blockIdx.x * 128;
    const int bn = blockIdx.y * BN;

    const int lrow = lane >> 2;
    const int lcol = (lane & 3) * 8;
    const uint16_t* gA0 = A + (size_t)(bm + wave * 32 + lrow) * K + lcol;
    const uint16_t* gA1 = gA0 + (size_t)16 * K;
    uint16_t* lA0 = sA + (wave * 2 + 0) * 512;
    uint16_t* lA1 = sA + (wave * 2 + 1) * 512;
    const uint16_t* gB0;
    const uint16_t* gB1 = nullptr;
    uint16_t* lB0;
    uint16_t* lB1 = nullptr;
    if constexpr (BN == 128) {
        gB0 = BT + (size_t)(bn + wave * 32 + lrow) * K + lcol;
        gB1 = gB0 + (size_t)16 * K;
        lB0 = sB + (wave * 2 + 0) * 512;
        lB1 = sB + (wave * 2 + 1) * 512;
    } else {
        gB0 = BT + (size_t)(bn + wave * 16 + lrow) * K + lcol;
        lB0 = sB + wave * 512;
    }

    const int fr = lane & 15;
    const int fg = lane >> 4;

    f32x4 acc[MF][4] = {};

    for (int k0 = 0; k0 < K; k0 += 32) {
        GLOAD_LDS(gA0 + k0, lA0);
        GLOAD_LDS(gA1 + k0, lA1);
        GLOAD_LDS(gB0 + k0, lB0);
        if constexpr (BN == 128) GLOAD_LDS(gB1 + k0, lB1);
        __syncthreads();

        bf16x8 af[MF], bfr[4];
#pragma unroll
        for (int m = 0; m < MF; ++m)
            af[m] = *(const bf16x8*)&sA[(wm * WROWS + m * 16 + fr) * 32 + fg * 8];
#pragma unroll
        for (int n = 0; n < 4; ++n)
            bfr[n] = *(const bf16x8*)&sB[(wn * 64 + n * 16 + fr) * 32 + fg * 8];
#pragma unroll
        for (int m = 0; m < MF; ++m)
#pragma unroll
            for (int n = 0; n < 4; ++n)
                acc[m][n] = __builtin_amdgcn_mfma_f32_16x16x32_bf16(
                    af[m], bfr[n], acc[m][n], 0, 0, 0);
        __syncthreads();
    }

#pragma unroll
    for (int m = 0; m < MF; ++m)
#pragma unroll
        for (int n = 0; n < 4; ++n) {
            const int col = bn + wn * 64 + n * 16 + fr;
#pragma unroll
            for (int r = 0; r < 4; ++r) {
                const int row = bm + wm * WROWS + m * 16 + fg * 4 + r;
                C[(size_t)row * N + col] = acc[m][n][r];
            }
        }
}

// ---------------------------------------------------------------------------
// x (4096x1024 f32) -> A' (4096x3072 bf16) = [hi | lo | hi]
// ---------------------------------------------------------------------------
__global__ __launch_bounds__(256) void cvt_x_split(const float* __restrict__ x,
                                                   uint16_t* __restrict__ a1) {
    const int i = blockIdx.x * 256 + threadIdx.x;
    const int m = i >> 8;
    const int c = (i & 255) << 2;
    const float4 v = ((const float4*)x)[i];
    uint16_t h[4], l[4];
    const float vf[4] = {v.x, v.y, v.z, v.w};
#pragma unroll
    for (int j = 0; j < 4; ++j) {
        h[j] = f2bf(vf[j]);
        l[j] = f2bf(vf[j] - bf2f(h[j]));
    }
    const size_t base = (size_t)m * 3072 + c;
    *(ushort4*)&a1[base]        = *(ushort4*)h;
    *(ushort4*)&a1[base + 1024] = *(ushort4*)l;
    *(ushort4*)&a1[base + 2048] = *(ushort4*)h;
}

// ---------------------------------------------------------------------------
// in_proj_w (1024x4096 f32) -> B'T (4096x3072 bf16): row n = [hi | hi | lo]
// ---------------------------------------------------------------------------
__global__ __launch_bounds__(256) void cvt_wT_split(const float* __restrict__ w,
                                                    uint16_t* __restrict__ bt) {
    __shared__ float s[32][33];
    const int tid = threadIdx.x;
    const int k0 = blockIdx.x * 32;
    const int n0 = blockIdx.y * 32;
#pragma unroll
    for (int p = 0; p < 4; ++p) {
        int lin = tid + p * 256;
        int i = lin >> 5, j = lin & 31;
        s[i][j] = w[(size_t)(k0 + i) * 4096 + n0 + j];
    }
    __syncthreads();
    const int r = tid >> 3, c4 = (tid & 7) * 4;
    uint16_t h[4], l[4];
#pragma unroll
    for (int j = 0; j < 4; ++j) {
        float v = s[c4 + j][r];
        h[j] = f2bf(v);
        l[j] = f2bf(v - bf2f(h[j]));
    }
    const size_t base = (size_t)(n0 + r) * 3072 + k0 + c4;
    *(ushort4*)&bt[base]        = *(ushort4*)h;
    *(ushort4*)&bt[base + 1024] = *(ushort4*)h;
    *(ushort4*)&bt[base + 2048] = *(ushort4*)l;
}

// ---------------------------------------------------------------------------
// out_proj_w (2048x1024 f32) -> opwT (1024x2048 bf16), plain hi.
// ---------------------------------------------------------------------------
__global__ __launch_bounds__(256) void cvt_opwT(const float* __restrict__ w,
                                                uint16_t* __restrict__ bt) {
    __shared__ float s[32][33];
    const int tid = threadIdx.x;
    const int k0 = blockIdx.x * 32;
    const int n0 = blockIdx.y * 32;
#pragma unroll
    for (int p = 0; p < 4; ++p) {
        int lin = tid + p * 256;
        int i = lin >> 5, j = lin & 31;
        s[i][j] = w[(size_t)(k0 + i) * 1024 + n0 + j];
    }
    __syncthreads();
    const int r = tid >> 3, c4 = (tid & 7) * 4;
    uint16_t h[4];
#pragma unroll
    for (int j = 0; j < 4; ++j) h[j] = f2bf(s[c4 + j][r]);
    *(ushort4*)&bt[(size_t)(n0 + r) * 2048 + k0 + c4] = *(ushort4*)h;
}

// ---------------------------------------------------------------------------
// Causal depthwise conv (D_CONV=4) + bias + SiLU.
// ---------------------------------------------------------------------------
__global__ __launch_bounds__(256) void conv_silu(const float* __restrict__ xz,
                                                 const float* __restrict__ conv_w,
                                                 const float* __restrict__ conv_b,
                                                 float* __restrict__ xc_act) {
    int idx = blockIdx.x * 256 + threadIdx.x;
    int d = idx & (D_INNER - 1);
    int r = idx >> 11;
    int t = r & (SEQ - 1);
    float acc = conv_b[d];
#pragma unroll
    for (int k = 0; k < D_CONV; ++k) {
        int tt = t + k - (D_CONV - 1);
        if (tt >= 0)
            acc = fmaf(xz[(size_t)(r + k - (D_CONV - 1)) * (2 * D_INNER) + d],
                       conv_w[d * D_CONV + k], acc);
    }
    float s = acc / (1.f + __expf(-acc));
    xc_act[(size_t)r * D_INNER + d] = s;
}

// ---------------------------------------------------------------------------
// x_dbl = xc_act (NROW x D_INNER) @ x_proj_w (D_INNER x 96). BM=32, full N=96.
// ---------------------------------------------------------------------------
__global__ __launch_bounds__(256) void xdbl_gemm(const float* __restrict__ A,
                                                 const float* __restrict__ W,
                                                 float* __restrict__ out) {
    __shared__ float As[32][132];
    __shared__ float Ws[128][96];
    const int tid = threadIdx.x;
    const int bm = blockIdx.x * 32;
    const int tc = tid & 31;
    const int tr = tid >> 5;
    float acc[4][3];
#pragma unroll
    for (int i = 0; i < 4; ++i)
#pragma unroll
        for (int j = 0; j < 3; ++j) acc[i][j] = 0.f;

    for (int k0 = 0; k0 < D_INNER; k0 += 128) {
#pragma unroll
        for (int l = 0; l < 4; ++l) {
            int i = tid + l * 256;
            int r = i >> 5, c4 = (i & 31) << 2;
            *(float4*)&As[r][c4] = *(const float4*)(A + (size_t)(bm + r) * D_INNER + k0 + c4);
        }
#pragma unroll
        for (int l = 0; l < 12; ++l) {
            int i = tid + l * 256;
            int r = i / 24, c4 = (i % 24) << 2;
            *(float4*)&Ws[r][c4] = *(const float4*)(W + (size_t)(k0 + r) * XPROJ_N + c4);
        }
        __syncthreads();
#pragma unroll 8
        for (int k = 0; k < 128; ++k) {
            float a0 = As[tr * 4 + 0][k], a1 = As[tr * 4 + 1][k];
            float a2 = As[tr * 4 + 2][k], a3 = As[tr * 4 + 3][k];
            float w0 = Ws[k][tc * 3 + 0], w1 = Ws[k][tc * 3 + 1], w2 = Ws[k][tc * 3 + 2];
            acc[0][0] = fmaf(a0, w0, acc[0][0]); acc[0][1] = fmaf(a0, w1, acc[0][1]); acc[0][2] = fmaf(a0, w2, acc[0][2]);
            acc[1][0] = fmaf(a1, w0, acc[1][0]); acc[1][1] = fmaf(a1, w1, acc[1][1]); acc[1][2] = fmaf(a1, w2, acc[1][2]);
            acc[2][0] = fmaf(a2, w0, acc[2][0]); acc[2][1] = fmaf(a2, w1, acc[2][1]); acc[2][2] = fmaf(a2, w2, acc[2][2]);
            acc[3][0] = fmaf(a3, w0, acc[3][0]); acc[3][1] = fmaf(a3, w1, acc[3][1]); acc[3][2] = fmaf(a3, w2, acc[3][2]);
        }
        __syncthreads();
    }
#pragma unroll
    for (int i = 0; i < 4; ++i)
#pragma unroll
        for (int j = 0; j < 3; ++j)
            out[(size_t)(bm + tr * 4 + i) * XPROJ_N + tc * 3 + j] = acc[i][j];
}

// ---------------------------------------------------------------------------
// dlt = softplus(x_dbl[:, :64] @ dt_proj_w + dt_proj_b).  K=64, tiles 64x64.
// ---------------------------------------------------------------------------
__global__ __launch_bounds__(256) void dt_gemm(const float* __restrict__ xdbl,
                                               const float* __restrict__ W,
                                               const float* __restrict__ bias,
                                               float* __restrict__ out) {
    __shared__ float As[64][68];
    __shared__ float Ws[64][64];
    const int tid = threadIdx.x;
    const int bm = blockIdx.x * 64, bn = blockIdx.y * 64;
#pragma unroll
    for (int l = 0; l < 4; ++l) {
        int i = tid + l * 256;
        int r = i >> 4, q4 = (i & 15) << 2;
        float4 v = *(const float4*)(xdbl + (size_t)(bm + r) * XPROJ_N + q4);
        As[q4 + 0][r] = v.x; As[q4 + 1][r] = v.y; As[q4 + 2][r] = v.z; As[q4 + 3][r] = v.w;
    }
#pragma unroll
    for (int l = 0; l < 4; ++l) {
        int i = tid + l * 256;
        int q = i >> 4, c4 = (i & 15) << 2;
        *(float4*)&Ws[q][c4] = *(const float4*)(W + (size_t)q * D_INNER + bn + c4);
    }
    __syncthreads();
    const int tx = tid & 15, ty = tid >> 4;
    float acc[4][4];
#pragma unroll
    for (int i = 0; i < 4; ++i)
#pragma unroll
        for (int j = 0; j < 4; ++j) acc[i][j] = 0.f;
#pragma unroll 16
    for (int k = 0; k < 64; ++k) {
        float a[4], w[4];
        *(float4*)a = *(const float4*)&As[k][ty * 4];
        *(float4*)w = *(const float4*)&Ws[k][tx * 4];
#pragma unroll
        for (int i = 0; i < 4; ++i)
#pragma unroll
            for (int j = 0; j < 4; ++j)
                acc[i][j] = fmaf(a[i], w[j], acc[i][j]);
    }
#pragma unroll
    for (int i = 0; i < 4; ++i) {
#pragma unroll
        for (int j = 0; j < 4; ++j) {
            float v = acc[i][j] + bias[bn + tx * 4 + j];
            float sp = fmaxf(v, 0.f) + log1pf(__expf(-fabsf(v)));
            out[(size_t)(bm + ty * 4 + i) * D_INNER + bn + tx * 4 + j] = sp;
        }
    }
}

// ---------------------------------------------------------------------------
// Chunked selective scan; carries live in the dead xc-half of xz.
// ---------------------------------------------------------------------------
__device__ __forceinline__ size_t hole(size_t i) {
    return (i >> 11) * 4096 + (i & 2047);
}

__global__ __launch_bounds__(256) void scan_pass1(const float* __restrict__ dlt,
                                                  const float* __restrict__ xc,
                                                  const float* __restrict__ xdbl,
                                                  const float* __restrict__ A_log,
                                                  float* __restrict__ carry) {
    __shared__ float s_B[CL][16];
    const int tid = threadIdx.x;
    const int bid = blockIdx.x;
    const int dg = bid & 7;
    const int c  = (bid >> 3) & (NCHUNK - 1);
    const int b  = bid >> 9;
    const int d  = dg * 256 + tid;
    const size_t rowbase = (size_t)b * SEQ + c * CL;

    float An[16];
    {
        float tmp[16];
        *(float4*)&tmp[0]  = *(const float4*)&A_log[d * 16 + 0];
        *(float4*)&tmp[4]  = *(const float4*)&A_log[d * 16 + 4];
        *(float4*)&tmp[8]  = *(const float4*)&A_log[d * 16 + 8];
        *(float4*)&tmp[12] = *(const float4*)&A_log[d * 16 + 12];
#pragma unroll
        for (int n = 0; n < 16; ++n) An[n] = -__expf(tmp[n]);
    }

#pragma unroll
    for (int p = 0; p < CL * 16 / 256; ++p) {
        int i = tid + p * 256;
        int t = i >> 4, n = i & 15;
        s_B[t][n] = xdbl[(rowbase + t) * (size_t)XPROJ_N + DT_RANK + n];
    }
    __syncthreads();

    float h[16], pA[16];
#pragma unroll
    for (int n = 0; n < 16; ++n) { h[n] = 0.f; pA[n] = 1.f; }

    const float* dtp = dlt + rowbase * D_INNER + d;
    const float* xvp = xc + rowbase * D_INNER + d;

    for (int tb = 0; tb < CL; tb += 4) {
        float dtv[4], xvv[4];
#pragma unroll
        for (int s = 0; s < 4; ++s) {
            dtv[s] = dtp[(size_t)(tb + s) * D_INNER];
            xvv[s] = xvp[(size_t)(tb + s) * D_INNER];
        }
#pragma unroll
        for (int s = 0; s < 4; ++s) {
            float Bv[16];
            *(float4*)&Bv[0]  = *(const float4*)&s_B[tb + s][0];
            *(float4*)&Bv[4]  = *(const float4*)&s_B[tb + s][4];
            *(float4*)&Bv[8]  = *(const float4*)&s_B[tb + s][8];
            *(float4*)&Bv[12] = *(const float4*)&s_B[tb + s][12];
            float du = dtv[s] * xvv[s];
#pragma unroll
            for (int n = 0; n < 16; ++n) {
                float dA = __expf(dtv[s] * An[n]);
                pA[n] *= dA;
                h[n] = fmaf(dA, h[n], du * Bv[n]);
            }
        }
    }

    size_t ci = (((size_t)b * NCHUNK + c) * D_INNER + d) * 16;
    float* pp = carry + hole(ci);
    float* hp = carry + hole(ci + ((size_t)1 << 22));
    *(float4*)&pp[0]  = *(float4*)&pA[0];  *(float4*)&pp[4]  = *(float4*)&pA[4];
    *(float4*)&pp[8]  = *(float4*)&pA[8];  *(float4*)&pp[12] = *(float4*)&pA[12];
    *(float4*)&hp[0]  = *(float4*)&h[0];   *(float4*)&hp[4]  = *(float4*)&h[4];
    *(float4*)&hp[8]  = *(float4*)&h[8];   *(float4*)&hp[12] = *(float4*)&h[12];
}

__global__ __launch_bounds__(256) void scan_pass2(float* __restrict__ carry) {
    int idx = blockIdx.x * 256 + threadIdx.x;
    int n = idx & 15;
    int d = (idx >> 4) & (D_INNER - 1);
    int b = idx >> 15;
    float prev = 0.f;
    for (int c = 0; c < NCHUNK; ++c) {
        size_t ci = (((size_t)b * NCHUNK + c) * D_INNER + d) * 16 + n;
        size_t op = hole(ci);
        size_t oh = op + (size_t)2048 * 4096;
        float p = carry[op];
        float e = carry[oh];
        carry[oh] = prev;
        prev = fmaf(p, prev, e);
    }
}

__global__ __launch_bounds__(256) void scan_pass3(const float* __restrict__ dlt,
                                                  const float* __restrict__ xc,
                                                  const float* __restrict__ xdbl,
                                                  const float* __restrict__ xz,
                                                  const float* __restrict__ A_log,
                                                  const float* __restrict__ Dvec,
                                                  const float* __restrict__ carry,
                                                  uint16_t* __restrict__ ygb) {
    __shared__ float s_B[CL][16];
    __shared__ float s_C[CL][16];
    const int tid = threadIdx.x;
    const int bid = blockIdx.x;
    const int dg = bid & 7;
    const int c  = (bid >> 3) & (NCHUNK - 1);
    const int b  = bid >> 9;
    const int d  = dg * 256 + tid;
    const size_t rowbase = (size_t)b * SEQ + c * CL;

    float An[16];
    {
        float tmp[16];
        *(float4*)&tmp[0]  = *(const float4*)&A_log[d * 16 + 0];
        *(float4*)&tmp[4]  = *(const float4*)&A_log[d * 16 + 4];
        *(float4*)&tmp[8]  = *(const float4*)&A_log[d * 16 + 8];
        *(float4*)&tmp[12] = *(const float4*)&A_log[d * 16 + 12];
#pragma unroll
        for (int n = 0; n < 16; ++n) An[n] = -__expf(tmp[n]);
    }
    const float Dd = Dvec[d];

#pragma unroll
    for (int p = 0; p < CL * 32 / 256; ++p) {
        int i = tid + p * 256;
        int t = i >> 5, col = i & 31;
        float v = xdbl[(rowbase + t) * (size_t)XPROJ_N + DT_RANK + col];
        if (col < 16) s_B[t][col] = v;
        else          s_C[t][col - 16] = v;
    }
    __syncthreads();

    float h[16];
    {
        size_t ci = (((size_t)b * NCHUNK + c) * D_INNER + d) * 16;
        const float* hp = carry + hole(ci + ((size_t)1 << 22));
        *(float4*)&h[0]  = *(const float4*)&hp[0];
        *(float4*)&h[4]  = *(const float4*)&hp[4];
        *(float4*)&h[8]  = *(const float4*)&hp[8];
        *(float4*)&h[12] = *(const float4*)&hp[12];
    }

    const float* dtp = dlt + rowbase * D_INNER + d;
    const float* xvp = xc + rowbase * D_INNER + d;
    const float* zp  = xz + rowbase * (size_t)(2 * D_INNER) + D_INNER + d;
    uint16_t* yp = ygb + rowbase * D_INNER + d;

    for (int tb = 0; tb < CL; tb += 4) {
        float dtv[4], xvv[4], zv[4];
#pragma unroll
        for (int s = 0; s < 4; ++s) {
            dtv[s] = dtp[(size_t)(tb + s) * D_INNER];
            xvv[s] = xvp[(size_t)(tb + s) * D_INNER];
            zv[s]  = zp[(size_t)(tb + s) * (2 * D_INNER)];
        }
#pragma unroll
        for (int s = 0; s < 4; ++s) {
            float Bv[16], Cv[16];
            *(float4*)&Bv[0]  = *(const float4*)&s_B[tb + s][0];
            *(float4*)&Bv[4]  = *(const float4*)&s_B[tb + s][4];
            *(float4*)&Bv[8]  = *(const float4*)&s_B[tb + s][8];
            *(float4*)&Bv[12] = *(const float4*)&s_B[tb + s][12];
            *(float4*)&Cv[0]  = *(const float4*)&s_C[tb + s][0];
            *(float4*)&Cv[4]  = *(const float4*)&s_C[tb + s][4];
            *(float4*)&Cv[8]  = *(const float4*)&s_C[tb + s][8];
            *(float4*)&Cv[12] = *(const float4*)&s_C[tb + s][12];
            float du = dtv[s] * xvv[s];
            float y = 0.f;
#pragma unroll
            for (int n = 0; n < 16; ++n) {
                float dA = __expf(dtv[s] * An[n]);
                h[n] = fmaf(dA, h[n], du * Bv[n]);
                y = fmaf(h[n], Cv[n], y);
            }
            y = fmaf(xvv[s], Dd, y);
            float sz = zv[s] / (1.f + __expf(-zv[s]));
            yp[(size_t)(tb + s) * D_INNER] = f2bf(y * sz);
        }
    }
}

// ---------------------------------------------------------------------------
extern "C" void kernel_launch(void* const* d_in, const int* in_sizes, int n_in,
                              void* d_out, int out_size, void* d_ws, size_t ws_size,
                              hipStream_t stream) {
    const float* x          = (const float*)d_in[0];
    const float* in_proj_w  = (const float*)d_in[1];
    const float* conv_w     = (const float*)d_in[2];
    const float* conv_b     = (const float*)d_in[3];
    const float* x_proj_w   = (const float*)d_in[4];
    const float* dt_proj_w  = (const float*)d_in[5];
    const float* dt_proj_b  = (const float*)d_in[6];
    const float* A_log      = (const float*)d_in[7];
    const float* Dvec       = (const float*)d_in[8];
    const float* out_proj_w = (const float*)d_in[9];
    float* out = (float*)d_out;

    // f32 workspace regions
    float* xz     = (float*)d_ws;                          // 64MB
    float* xc_act = xz + (size_t)NROW * 2 * D_INNER;       // 32MB
    float* x_dbl  = xc_act + (size_t)NROW * D_INNER;       // 1.5MB
    float* dlt    = x_dbl + (size_t)NROW * XPROJ_N;        // 32MB
    // bf16 aliases with disjoint lifetimes:
    uint16_t* A1   = (uint16_t*)xc_act;                    // dead before conv_silu
    uint16_t* B1T  = (uint16_t*)x_dbl;                     // dead before xdbl_gemm
    uint16_t* ygb  = (uint16_t*)(dlt + (size_t)NROW * D_INNER);  // 16MB fresh
    uint16_t* opwT = ygb + (size_t)NROW * D_INNER;               //  4MB fresh

    // allow 128 KB dynamic LDS for the 8-phase GEMM (host-side, capture-safe)
    (void)hipFuncSetAttribute((const void*)gemm256_8p,
                              hipFuncAttributeMaxDynamicSharedMemorySize, 131072);

    // 1) split-bf16 operand prep for GEMM1
    cvt_x_split<<<(NROW * D_MODEL / 4) / 256, 256, 0, stream>>>(x, A1);
    cvt_wT_split<<<dim3(D_MODEL / 32, (2 * D_INNER) / 32), 256, 0, stream>>>(in_proj_w, B1T);
    // 2) xz = x @ in_proj_w  via 256^2 8-phase bf16 MFMA, K' = 3072 exact split
    gemm256_8p<<<dim3(NROW / 256, (2 * D_INNER) / 256), 512, 131072, stream>>>(
        A1, B1T, xz, NROW, 2 * D_INNER, 3 * D_MODEL);
    // 3) conv + silu
    conv_silu<<<(NROW * D_INNER) / 256, 256, 0, stream>>>(xz, conv_w, conv_b, xc_act);
    // 4) x_dbl = xc_act @ x_proj_w
    xdbl_gemm<<<NROW / 32, 256, 0, stream>>>(xc_act, x_proj_w, x_dbl);
    // 5) dlt = softplus(x_dbl[:, :64] @ dt_proj_w + b)
    dt_gemm<<<dim3(NROW / 64, D_INNER / 64), 256, 0, stream>>>(x_dbl, dt_proj_w, dt_proj_b, dlt);
    // 6) chunked selective scan; pass3 writes y_gated directly as bf16
    scan_pass1<<<BATCH * NCHUNK * 8, 256, 0, stream>>>(dlt, xc_act, x_dbl, A_log, xz);
    scan_pass2<<<(BATCH * D_INNER * 16) / 256, 256, 0, stream>>>(xz);
    scan_pass3<<<BATCH * NCHUNK * 8, 256, 0, stream>>>(dlt, xc_act, x_dbl, xz,
                                                       A_log, Dvec, xz, ygb);
    // 7) out-projection operand prep + bf16 GEMM2 (skinny-N tile)
    cvt_opwT<<<dim3(D_INNER / 32, D_MODEL / 32), 256, 0, stream>>>(out_proj_w, opwT);
    gemm_bf16_bt<64><<<dim3(NROW / 128, D_MODEL / 64), 256, 0, stream>>>(
        ygb, opwT, out, NROW, D_MODEL, D_INNER);
}

// Round 8
// 417.339 us; speedup vs baseline: 1.1471x; 1.0140x over previous
//
#include <hip/hip_runtime.h>
#include <hip/hip_bf16.h>
#include <stdint.h>

#define D_MODEL 1024
#define D_STATE 16
#define D_CONV 4
#define D_INNER 2048
#define DT_RANK 64
#define BATCH 2
#define SEQ 2048
#define NROW (BATCH * SEQ)          // 4096
#define XPROJ_N (DT_RANK + 2 * D_STATE)  // 96
#define NCHUNK 64                   // time chunks for scan decomposition
#define CL 32                       // SEQ / NCHUNK

typedef __bf16 bf16x8 __attribute__((ext_vector_type(8)));
typedef float  f32x4  __attribute__((ext_vector_type(4)));

// RNE f32 -> bf16 (bit trick; inputs are tame, no NaN handling needed)
__device__ __forceinline__ uint16_t f2bf(float f) {
    uint32_t u = __float_as_uint(f);
    u += 0x7FFFu + ((u >> 16) & 1u);
    return (uint16_t)(u >> 16);
}
__device__ __forceinline__ float bf2f(uint16_t h) {
    return __uint_as_float((uint32_t)h << 16);
}

#define GLOAD_LDS(g, l) __builtin_amdgcn_global_load_lds(                      \
    (const __attribute__((address_space(1))) void*)(g),                        \
    (__attribute__((address_space(3))) void*)(l), 16, 0, 0)

// ===========================================================================
// 256x256 8-phase bf16 GEMM (T2 swizzle + T3/T4 counted vmcnt + T5 setprio).
// C(MxN,f32) = A(MxK,bf16) @ BT(NxK,bf16)^T.  Grid (M/256, N/256), 512 thr.
// LDS 128 KB: buf{0,1} x {A,B} x half{0,1} x 8192 elems (128 rows x 64 k).
//
// SWIZZLE (R7 fix): row stride = 128 B = full bank space, so a 16-row frag
// read is natively 16-way bank-conflicted. Permute col-slot by row low bits:
//   elem:  col ^= (row & 7) << 3     (byte: ^= (row&7)<<4)
// -> 16 rows cover 8 slots x 2 lanes = 2-way = free. Applied as swizzled
// ds_read + pre-swizzled GLOBAL source (gload_lds dest stays linear):
// phys row ≡ (lane>>3) (mod 8) for every STAGE segment, so source col group
// = (lane&7) ^ ((lane>>3)&7).  [R7: 1-bit swizzle left 9.4e6 conflicts]
//
// Stage stream (iter i, tiles T0=2i buf0, T1=2i+1 buf1):
//   ph1:A0(T1) ph2:A1(T1) ph3:B0(T0+2) ph4:B1(T0+2)+vmcnt(4)
//   ph5:A0(T0+2) ph6:A1(T0+2) ph7:B0(T1+2) ph8:B1(T1+2)+vmcnt(4)
// FIFO ledger: vmcnt(4) at ph4 retires {B0,B1(T1), A0,A1(T1)} => T1 resident
// at ph5; vmcnt(4) at ph8 retires all of T0+2 => resident at next ph1.
// ===========================================================================
#define LDA8(BUF, MH) do {                                                     \
  _Pragma("unroll") for (int m_ = 0; m_ < 4; ++m_)                             \
    _Pragma("unroll") for (int ks_ = 0; ks_ < 2; ++ks_) {                      \
      int e_ = (((MH)*64 + m_*16 + fr) << 6) + ks_*32 + fg*8;                  \
      e_ ^= ((e_ >> 6) & 7) << 3;                                              \
      a[m_][ks_] = *(const bf16x8*)&lds[(BUF)*32768 + wm*8192 + e_];           \
    }                                                                          \
} while (0)

#define LDB4(BUF, NH) do {                                                     \
  _Pragma("unroll") for (int n_ = 0; n_ < 2; ++n_)                             \
    _Pragma("unroll") for (int ks_ = 0; ks_ < 2; ++ks_) {                      \
      int e_ = ((((wn & 1)*64) + (NH)*32 + n_*16 + fr) << 6) + ks_*32 + fg*8;  \
      e_ ^= ((e_ >> 6) & 7) << 3;                                              \
      bb[NH][n_][ks_] = *(const bf16x8*)&lds[(BUF)*32768 + 16384 +             \
                                             (wn >> 1)*8192 + e_];             \
    }                                                                          \
} while (0)

#define MFMA16(MH, NH) do {                                                    \
  __builtin_amdgcn_s_setprio(1);                                               \
  _Pragma("unroll") for (int m_ = 0; m_ < 4; ++m_)                             \
    _Pragma("unroll") for (int n_ = 0; n_ < 2; ++n_)                           \
      _Pragma("unroll") for (int ks_ = 0; ks_ < 2; ++ks_)                      \
        acc[(MH)*4 + m_][(NH)*2 + n_] = __builtin_amdgcn_mfma_f32_16x16x32_bf16( \
            a[m_][ks_], bb[NH][n_][ks_], acc[(MH)*4 + m_][(NH)*2 + n_], 0, 0, 0); \
  __builtin_amdgcn_s_setprio(0);                                               \
} while (0)

#define STAGE(MAT, HALF, T) do {                                               \
  if ((T) < NT) {                                                              \
    const uint16_t* s0_ = ((MAT) ? Bs0 : As0) + (size_t)(HALF)*128*K + (size_t)(T)*64; \
    const uint16_t* s1_ = ((MAT) ? Bs1 : As1) + (size_t)(HALF)*128*K + (size_t)(T)*64; \
    uint16_t* d_ = lds + (((T) & 1)*32768 + (MAT)*16384 + (HALF)*8192 + wave*512); \
    GLOAD_LDS(s0_, d_);                                                        \
    GLOAD_LDS(s1_, d_ + 4096);                                                 \
  }                                                                            \
} while (0)

#define BAR()  __builtin_amdgcn_s_barrier()
#define LGKM0() do { asm volatile("s_waitcnt lgkmcnt(0)" ::: "memory");        \
                     __builtin_amdgcn_sched_barrier(0); } while (0)
#define VM4()  do { asm volatile("s_waitcnt vmcnt(4)" ::: "memory");           \
                    __builtin_amdgcn_sched_barrier(0); } while (0)

__global__ __launch_bounds__(512, 2) void gemm256_8p(const uint16_t* __restrict__ A,
                                                     const uint16_t* __restrict__ BT,
                                                     float* __restrict__ C,
                                                     int M, int N, int K) {
    extern __shared__ uint16_t lds[];           // 131072 bytes
    const int tid  = threadIdx.x;
    const int wave = tid >> 6, lane = tid & 63;
    const int wm = wave >> 2, wn = wave & 3;    // 2M x 4N wave grid
    const int fr = lane & 15, fg = lane >> 4;
    const int bm = blockIdx.x * 256, bn = blockIdx.y * 256;
    const int NT = K >> 6;                      // number of K-tiles (BK=64)
    const int NIT = NT >> 1;

    // staging source (pre-swizzled global): phys row = wave*8 + (lane>>3)
    // (+64/+128 offsets preserve row mod 8); logical k-col group =
    // (lane&7) ^ ((lane>>3)&7)  [inverse of the read swizzle]
    const int srow = wave * 8 + (lane >> 3);
    const int skcol = (((lane & 7) ^ ((lane >> 3) & 7)) * 8);
    const uint16_t* As0 = A  + (size_t)(bm + srow) * K + skcol;
    const uint16_t* As1 = A  + (size_t)(bm + srow + 64) * K + skcol;
    const uint16_t* Bs0 = BT + (size_t)(bn + srow) * K + skcol;
    const uint16_t* Bs1 = BT + (size_t)(bn + srow + 64) * K + skcol;

    f32x4 acc[8][4] = {};
    bf16x8 a[4][2];
    bf16x8 bb[2][2][2];

    // prologue: tile0 (all 4 halves) + tile1 B halves; drain to 4 outstanding
    STAGE(0, 0, 0); STAGE(0, 1, 0); STAGE(1, 0, 0); STAGE(1, 1, 0);
    STAGE(1, 0, 1); STAGE(1, 1, 1);
    VM4(); BAR();

    for (int i = 0; i < NIT; ++i) {
        const int T0 = 2 * i, T1 = 2 * i + 1;
        // ---- K-step T0 (buf0) ----
        LDA8(0, 0); LDB4(0, 0); STAGE(0, 0, T1);
        BAR(); LGKM0(); MFMA16(0, 0); BAR();
        LDB4(0, 1);             STAGE(0, 1, T1);
        BAR(); LGKM0(); MFMA16(0, 1); BAR();
        LDA8(0, 1);             STAGE(1, 0, T0 + 2);
        BAR(); LGKM0(); MFMA16(1, 0); BAR();
                                STAGE(1, 1, T0 + 2);
        VM4();
        BAR(); LGKM0(); MFMA16(1, 1); BAR();
        // ---- K-step T1 (buf1) ----
        LDA8(1, 0); LDB4(1, 0); STAGE(0, 0, T0 + 2);
        BAR(); LGKM0(); MFMA16(0, 0); BAR();
        LDB4(1, 1);             STAGE(0, 1, T0 + 2);
        BAR(); LGKM0(); MFMA16(0, 1); BAR();
        LDA8(1, 1);             STAGE(1, 0, T1 + 2);
        BAR(); LGKM0(); MFMA16(1, 0); BAR();
                                STAGE(1, 1, T1 + 2);
        VM4();
        BAR(); LGKM0(); MFMA16(1, 1); BAR();
    }

    // epilogue: C/D layout col = lane&15, row = (lane>>4)*4 + reg
    const int crow0 = bm + wm * 128 + fg * 4;
    const int ccol0 = bn + wn * 64 + fr;
#pragma unroll
    for (int mp = 0; mp < 8; ++mp)
#pragma unroll
        for (int np = 0; np < 4; ++np)
#pragma unroll
            for (int r = 0; r < 4; ++r)
                C[(size_t)(crow0 + mp * 16 + r) * N + ccol0 + np * 16] = acc[mp][np][r];
}

// ---------------------------------------------------------------------------
// m97-structure bf16 GEMM for skinny N (GEMM2). BN=64: 4x1 waves, 32x64/wave.
// ---------------------------------------------------------------------------
template <int BN>
__global__ __launch_bounds__(256) void gemm_bf16_bt(const uint16_t* __restrict__ A,
                                                    const uint16_t* __restrict__ BT,
                                                    float* __restrict__ C,
                                                    int M, int N, int K) {
    constexpr int WROWS = (BN == 128) ? 64 : 32;
    constexpr int MF = WROWS / 16;
    __shared__ uint16_t sA[128 * 32];
    __shared__ uint16_t sB[BN * 32];
    const int tid  = threadIdx.x;
    const int wave = tid >> 6;
    const int lane = tid & 63;
    const int wm = (BN == 128) ? (wave >> 1) : wave;
    const int wn = (BN == 128) ? (wave & 1) : 0;
    const int bm = blockIdx.x * 128;
    const int bn = blockIdx.y * BN;

    const int lrow = lane >> 2;
    const int lcol = (lane & 3) * 8;
    const uint16_t* gA0 = A + (size_t)(bm + wave * 32 + lrow) * K + lcol;
    const uint16_t* gA1 = gA0 + (size_t)16 * K;
    uint16_t* lA0 = sA + (wave * 2 + 0) * 512;
    uint16_t* lA1 = sA + (wave * 2 + 1) * 512;
    const uint16_t* gB0;
    const uint16_t* gB1 = nullptr;
    uint16_t* lB0;
    uint16_t* lB1 = nullptr;
    if constexpr (BN == 128) {
        gB0 = BT + (size_t)(bn + wave * 32 + lrow) * K + lcol;
        gB1 = gB0 + (size_t)16 * K;
        lB0 = sB + (wave * 2 + 0) * 512;
        lB1 = sB + (wave * 2 + 1) * 512;
    } else {
        gB0 = BT + (size_t)(bn + wave * 16 + lrow) * K + lcol;
        lB0 = sB + wave * 512;
    }

    const int fr = lane & 15;
    const int fg = lane >> 4;

    f32x4 acc[MF][4] = {};

    for (int k0 = 0; k0 < K; k0 += 32) {
        GLOAD_LDS(gA0 + k0, lA0);
        GLOAD_LDS(gA1 + k0, lA1);
        GLOAD_LDS(gB0 + k0, lB0);
        if constexpr (BN == 128) GLOAD_LDS(gB1 + k0, lB1);
        __syncthreads();

        bf16x8 af[MF], bfr[4];
#pragma unroll
        for (int m = 0; m < MF; ++m)
            af[m] = *(const bf16x8*)&sA[(wm * WROWS + m * 16 + fr) * 32 + fg * 8];
#pragma unroll
        for (int n = 0; n < 4; ++n)
            bfr[n] = *(const bf16x8*)&sB[(wn * 64 + n * 16 + fr) * 32 + fg * 8];
#pragma unroll
        for (int m = 0; m < MF; ++m)
#pragma unroll
            for (int n = 0; n < 4; ++n)
                acc[m][n] = __builtin_amdgcn_mfma_f32_16x16x32_bf16(
                    af[m], bfr[n], acc[m][n], 0, 0, 0);
        __syncthreads();
    }

#pragma unroll
    for (int m = 0; m < MF; ++m)
#pragma unroll
        for (int n = 0; n < 4; ++n) {
            const int col = bn + wn * 64 + n * 16 + fr;
#pragma unroll
            for (int r = 0; r < 4; ++r) {
                const int row = bm + wm * WROWS + m * 16 + fg * 4 + r;
                C[(size_t)row * N + col] = acc[m][n][r];
            }
        }
}

// ---------------------------------------------------------------------------
// x (4096x1024 f32) -> A' (4096x3072 bf16) = [hi | lo | hi]
// ---------------------------------------------------------------------------
__global__ __launch_bounds__(256) void cvt_x_split(const float* __restrict__ x,
                                                   uint16_t* __restrict__ a1) {
    const int i = blockIdx.x * 256 + threadIdx.x;
    const int m = i >> 8;
    const int c = (i & 255) << 2;
    const float4 v = ((const float4*)x)[i];
    uint16_t h[4], l[4];
    const float vf[4] = {v.x, v.y, v.z, v.w};
#pragma unroll
    for (int j = 0; j < 4; ++j) {
        h[j] = f2bf(vf[j]);
        l[j] = f2bf(vf[j] - bf2f(h[j]));
    }
    const size_t base = (size_t)m * 3072 + c;
    *(ushort4*)&a1[base]        = *(ushort4*)h;
    *(ushort4*)&a1[base + 1024] = *(ushort4*)l;
    *(ushort4*)&a1[base + 2048] = *(ushort4*)h;
}

// ---------------------------------------------------------------------------
// in_proj_w (1024x4096 f32) -> B'T (4096x3072 bf16): row n = [hi | hi | lo]
// ---------------------------------------------------------------------------
__global__ __launch_bounds__(256) void cvt_wT_split(const float* __restrict__ w,
                                                    uint16_t* __restrict__ bt) {
    __shared__ float s[32][33];
    const int tid = threadIdx.x;
    const int k0 = blockIdx.x * 32;
    const int n0 = blockIdx.y * 32;
#pragma unroll
    for (int p = 0; p < 4; ++p) {
        int lin = tid + p * 256;
        int i = lin >> 5, j = lin & 31;
        s[i][j] = w[(size_t)(k0 + i) * 4096 + n0 + j];
    }
    __syncthreads();
    const int r = tid >> 3, c4 = (tid & 7) * 4;
    uint16_t h[4], l[4];
#pragma unroll
    for (int j = 0; j < 4; ++j) {
        float v = s[c4 + j][r];
        h[j] = f2bf(v);
        l[j] = f2bf(v - bf2f(h[j]));
    }
    const size_t base = (size_t)(n0 + r) * 3072 + k0 + c4;
    *(ushort4*)&bt[base]        = *(ushort4*)h;
    *(ushort4*)&bt[base + 1024] = *(ushort4*)h;
    *(ushort4*)&bt[base + 2048] = *(ushort4*)l;
}

// ---------------------------------------------------------------------------
// out_proj_w (2048x1024 f32) -> opwT (1024x2048 bf16), plain hi.
// ---------------------------------------------------------------------------
__global__ __launch_bounds__(256) void cvt_opwT(const float* __restrict__ w,
                                                uint16_t* __restrict__ bt) {
    __shared__ float s[32][33];
    const int tid = threadIdx.x;
    const int k0 = blockIdx.x * 32;
    const int n0 = blockIdx.y * 32;
#pragma unroll
    for (int p = 0; p < 4; ++p) {
        int lin = tid + p * 256;
        int i = lin >> 5, j = lin & 31;
        s[i][j] = w[(size_t)(k0 + i) * 1024 + n0 + j];
    }
    __syncthreads();
    const int r = tid >> 3, c4 = (tid & 7) * 4;
    uint16_t h[4];
#pragma unroll
    for (int j = 0; j < 4; ++j) h[j] = f2bf(s[c4 + j][r]);
    *(ushort4*)&bt[(size_t)(n0 + r) * 2048 + k0 + c4] = *(ushort4*)h;
}

// ---------------------------------------------------------------------------
// Causal depthwise conv (D_CONV=4) + bias + SiLU.
// ---------------------------------------------------------------------------
__global__ __launch_bounds__(256) void conv_silu(const float* __restrict__ xz,
                                                 const float* __restrict__ conv_w,
                                                 const float* __restrict__ conv_b,
                                                 float* __restrict__ xc_act) {
    int idx = blockIdx.x * 256 + threadIdx.x;
    int d = idx & (D_INNER - 1);
    int r = idx >> 11;
    int t = r & (SEQ - 1);
    float acc = conv_b[d];
#pragma unroll
    for (int k = 0; k < D_CONV; ++k) {
        int tt = t + k - (D_CONV - 1);
        if (tt >= 0)
            acc = fmaf(xz[(size_t)(r + k - (D_CONV - 1)) * (2 * D_INNER) + d],
                       conv_w[d * D_CONV + k], acc);
    }
    float s = acc / (1.f + __expf(-acc));
    xc_act[(size_t)r * D_INNER + d] = s;
}

// ---------------------------------------------------------------------------
// x_dbl = xc_act (NROW x D_INNER) @ x_proj_w (D_INNER x 96). BM=32, full N=96.
// ---------------------------------------------------------------------------
__global__ __launch_bounds__(256) void xdbl_gemm(const float* __restrict__ A,
                                                 const float* __restrict__ W,
                                                 float* __restrict__ out) {
    __shared__ float As[32][132];
    __shared__ float Ws[128][96];
    const int tid = threadIdx.x;
    const int bm = blockIdx.x * 32;
    const int tc = tid & 31;
    const int tr = tid >> 5;
    float acc[4][3];
#pragma unroll
    for (int i = 0; i < 4; ++i)
#pragma unroll
        for (int j = 0; j < 3; ++j) acc[i][j] = 0.f;

    for (int k0 = 0; k0 < D_INNER; k0 += 128) {
#pragma unroll
        for (int l = 0; l < 4; ++l) {
            int i = tid + l * 256;
            int r = i >> 5, c4 = (i & 31) << 2;
            *(float4*)&As[r][c4] = *(const float4*)(A + (size_t)(bm + r) * D_INNER + k0 + c4);
        }
#pragma unroll
        for (int l = 0; l < 12; ++l) {
            int i = tid + l * 256;
            int r = i / 24, c4 = (i % 24) << 2;
            *(float4*)&Ws[r][c4] = *(const float4*)(W + (size_t)(k0 + r) * XPROJ_N + c4);
        }
        __syncthreads();
#pragma unroll 8
        for (int k = 0; k < 128; ++k) {
            float a0 = As[tr * 4 + 0][k], a1 = As[tr * 4 + 1][k];
            float a2 = As[tr * 4 + 2][k], a3 = As[tr * 4 + 3][k];
            float w0 = Ws[k][tc * 3 + 0], w1 = Ws[k][tc * 3 + 1], w2 = Ws[k][tc * 3 + 2];
            acc[0][0] = fmaf(a0, w0, acc[0][0]); acc[0][1] = fmaf(a0, w1, acc[0][1]); acc[0][2] = fmaf(a0, w2, acc[0][2]);
            acc[1][0] = fmaf(a1, w0, acc[1][0]); acc[1][1] = fmaf(a1, w1, acc[1][1]); acc[1][2] = fmaf(a1, w2, acc[1][2]);
            acc[2][0] = fmaf(a2, w0, acc[2][0]); acc[2][1] = fmaf(a2, w1, acc[2][1]); acc[2][2] = fmaf(a2, w2, acc[2][2]);
            acc[3][0] = fmaf(a3, w0, acc[3][0]); acc[3][1] = fmaf(a3, w1, acc[3][1]); acc[3][2] = fmaf(a3, w2, acc[3][2]);
        }
        __syncthreads();
    }
#pragma unroll
    for (int i = 0; i < 4; ++i)
#pragma unroll
        for (int j = 0; j < 3; ++j)
            out[(size_t)(bm + tr * 4 + i) * XPROJ_N + tc * 3 + j] = acc[i][j];
}

// ---------------------------------------------------------------------------
// dlt = softplus(x_dbl[:, :64] @ dt_proj_w + dt_proj_b).  K=64, tiles 64x64.
// ---------------------------------------------------------------------------
__global__ __launch_bounds__(256) void dt_gemm(const float* __restrict__ xdbl,
                                               const float* __restrict__ W,
                                               const float* __restrict__ bias,
                                               float* __restrict__ out) {
    __shared__ float As[64][68];
    __shared__ float Ws[64][64];
    const int tid = threadIdx.x;
    const int bm = blockIdx.x * 64, bn = blockIdx.y * 64;
#pragma unroll
    for (int l = 0; l < 4; ++l) {
        int i = tid + l * 256;
        int r = i >> 4, q4 = (i & 15) << 2;
        float4 v = *(const float4*)(xdbl + (size_t)(bm + r) * XPROJ_N + q4);
        As[q4 + 0][r] = v.x; As[q4 + 1][r] = v.y; As[q4 + 2][r] = v.z; As[q4 + 3][r] = v.w;
    }
#pragma unroll
    for (int l = 0; l < 4; ++l) {
        int i = tid + l * 256;
        int q = i >> 4, c4 = (i & 15) << 2;
        *(float4*)&Ws[q][c4] = *(const float4*)(W + (size_t)q * D_INNER + bn + c4);
    }
    __syncthreads();
    const int tx = tid & 15, ty = tid >> 4;
    float acc[4][4];
#pragma unroll
    for (int i = 0; i < 4; ++i)
#pragma unroll
        for (int j = 0; j < 4; ++j) acc[i][j] = 0.f;
#pragma unroll 16
    for (int k = 0; k < 64; ++k) {
        float a[4], w[4];
        *(float4*)a = *(const float4*)&As[k][ty * 4];
        *(float4*)w = *(const float4*)&Ws[k][tx * 4];
#pragma unroll
        for (int i = 0; i < 4; ++i)
#pragma unroll
            for (int j = 0; j < 4; ++j)
                acc[i][j] = fmaf(a[i], w[j], acc[i][j]);
    }
#pragma unroll
    for (int i = 0; i < 4; ++i) {
#pragma unroll
        for (int j = 0; j < 4; ++j) {
            float v = acc[i][j] + bias[bn + tx * 4 + j];
            float sp = fmaxf(v, 0.f) + log1pf(__expf(-fabsf(v)));
            out[(size_t)(bm + ty * 4 + i) * D_INNER + bn + tx * 4 + j] = sp;
        }
    }
}

// ---------------------------------------------------------------------------
// Chunked selective scan; carries live in the dead xc-half of xz.
// ---------------------------------------------------------------------------
__device__ __forceinline__ size_t hole(size_t i) {
    return (i >> 11) * 4096 + (i & 2047);
}

__global__ __launch_bounds__(256) void scan_pass1(const float* __restrict__ dlt,
                                                  const float* __restrict__ xc,
                                                  const float* __restrict__ xdbl,
                                                  const float* __restrict__ A_log,
                                                  float* __restrict__ carry) {
    __shared__ float s_B[CL][16];
    const int tid = threadIdx.x;
    const int bid = blockIdx.x;
    const int dg = bid & 7;
    const int c  = (bid >> 3) & (NCHUNK - 1);
    const int b  = bid >> 9;
    const int d  = dg * 256 + tid;
    const size_t rowbase = (size_t)b * SEQ + c * CL;

    float An[16];
    {
        float tmp[16];
        *(float4*)&tmp[0]  = *(const float4*)&A_log[d * 16 + 0];
        *(float4*)&tmp[4]  = *(const float4*)&A_log[d * 16 + 4];
        *(float4*)&tmp[8]  = *(const float4*)&A_log[d * 16 + 8];
        *(float4*)&tmp[12] = *(const float4*)&A_log[d * 16 + 12];
#pragma unroll
        for (int n = 0; n < 16; ++n) An[n] = -__expf(tmp[n]);
    }

#pragma unroll
    for (int p = 0; p < CL * 16 / 256; ++p) {
        int i = tid + p * 256;
        int t = i >> 4, n = i & 15;
        s_B[t][n] = xdbl[(rowbase + t) * (size_t)XPROJ_N + DT_RANK + n];
    }
    __syncthreads();

    float h[16], pA[16];
#pragma unroll
    for (int n = 0; n < 16; ++n) { h[n] = 0.f; pA[n] = 1.f; }

    const float* dtp = dlt + rowbase * D_INNER + d;
    const float* xvp = xc + rowbase * D_INNER + d;

    for (int tb = 0; tb < CL; tb += 4) {
        float dtv[4], xvv[4];
#pragma unroll
        for (int s = 0; s < 4; ++s) {
            dtv[s] = dtp[(size_t)(tb + s) * D_INNER];
            xvv[s] = xvp[(size_t)(tb + s) * D_INNER];
        }
#pragma unroll
        for (int s = 0; s < 4; ++s) {
            float Bv[16];
            *(float4*)&Bv[0]  = *(const float4*)&s_B[tb + s][0];
            *(float4*)&Bv[4]  = *(const float4*)&s_B[tb + s][4];
            *(float4*)&Bv[8]  = *(const float4*)&s_B[tb + s][8];
            *(float4*)&Bv[12] = *(const float4*)&s_B[tb + s][12];
            float du = dtv[s] * xvv[s];
#pragma unroll
            for (int n = 0; n < 16; ++n) {
                float dA = __expf(dtv[s] * An[n]);
                pA[n] *= dA;
                h[n] = fmaf(dA, h[n], du * Bv[n]);
            }
        }
    }

    size_t ci = (((size_t)b * NCHUNK + c) * D_INNER + d) * 16;
    float* pp = carry + hole(ci);
    float* hp = carry + hole(ci + ((size_t)1 << 22));
    *(float4*)&pp[0]  = *(float4*)&pA[0];  *(float4*)&pp[4]  = *(float4*)&pA[4];
    *(float4*)&pp[8]  = *(float4*)&pA[8];  *(float4*)&pp[12] = *(float4*)&pA[12];
    *(float4*)&hp[0]  = *(float4*)&h[0];   *(float4*)&hp[4]  = *(float4*)&h[4];
    *(float4*)&hp[8]  = *(float4*)&h[8];   *(float4*)&hp[12] = *(float4*)&h[12];
}

__global__ __launch_bounds__(256) void scan_pass2(float* __restrict__ carry) {
    int idx = blockIdx.x * 256 + threadIdx.x;
    int n = idx & 15;
    int d = (idx >> 4) & (D_INNER - 1);
    int b = idx >> 15;
    float prev = 0.f;
    for (int c = 0; c < NCHUNK; ++c) {
        size_t ci = (((size_t)b * NCHUNK + c) * D_INNER + d) * 16 + n;
        size_t op = hole(ci);
        size_t oh = op + (size_t)2048 * 4096;
        float p = carry[op];
        float e = carry[oh];
        carry[oh] = prev;
        prev = fmaf(p, prev, e);
    }
}

__global__ __launch_bounds__(256) void scan_pass3(const float* __restrict__ dlt,
                                                  const float* __restrict__ xc,
                                                  const float* __restrict__ xdbl,
                                                  const float* __restrict__ xz,
                                                  const float* __restrict__ A_log,
                                                  const float* __restrict__ Dvec,
                                                  const float* __restrict__ carry,
                                                  uint16_t* __restrict__ ygb) {
    __shared__ float s_B[CL][16];
    __shared__ float s_C[CL][16];
    const int tid = threadIdx.x;
    const int bid = blockIdx.x;
    const int dg = bid & 7;
    const int c  = (bid >> 3) & (NCHUNK - 1);
    const int b  = bid >> 9;
    const int d  = dg * 256 + tid;
    const size_t rowbase = (size_t)b * SEQ + c * CL;

    float An[16];
    {
        float tmp[16];
        *(float4*)&tmp[0]  = *(const float4*)&A_log[d * 16 + 0];
        *(float4*)&tmp[4]  = *(const float4*)&A_log[d * 16 + 4];
        *(float4*)&tmp[8]  = *(const float4*)&A_log[d * 16 + 8];
        *(float4*)&tmp[12] = *(const float4*)&A_log[d * 16 + 12];
#pragma unroll
        for (int n = 0; n < 16; ++n) An[n] = -__expf(tmp[n]);
    }
    const float Dd = Dvec[d];

#pragma unroll
    for (int p = 0; p < CL * 32 / 256; ++p) {
        int i = tid + p * 256;
        int t = i >> 5, col = i & 31;
        float v = xdbl[(rowbase + t) * (size_t)XPROJ_N + DT_RANK + col];
        if (col < 16) s_B[t][col] = v;
        else          s_C[t][col - 16] = v;
    }
    __syncthreads();

    float h[16];
    {
        size_t ci = (((size_t)b * NCHUNK + c) * D_INNER + d) * 16;
        const float* hp = carry + hole(ci + ((size_t)1 << 22));
        *(float4*)&h[0]  = *(const float4*)&hp[0];
        *(float4*)&h[4]  = *(const float4*)&hp[4];
        *(float4*)&h[8]  = *(const float4*)&hp[8];
        *(float4*)&h[12] = *(const float4*)&hp[12];
    }

    const float* dtp = dlt + rowbase * D_INNER + d;
    const float* xvp = xc + rowbase * D_INNER + d;
    const float* zp  = xz + rowbase * (size_t)(2 * D_INNER) + D_INNER + d;
    uint16_t* yp = ygb + rowbase * D_INNER + d;

    for (int tb = 0; tb < CL; tb += 4) {
        float dtv[4], xvv[4], zv[4];
#pragma unroll
        for (int s = 0; s < 4; ++s) {
            dtv[s] = dtp[(size_t)(tb + s) * D_INNER];
            xvv[s] = xvp[(size_t)(tb + s) * D_INNER];
            zv[s]  = zp[(size_t)(tb + s) * (2 * D_INNER)];
        }
#pragma unroll
        for (int s = 0; s < 4; ++s) {
            float Bv[16], Cv[16];
            *(float4*)&Bv[0]  = *(const float4*)&s_B[tb + s][0];
            *(float4*)&Bv[4]  = *(const float4*)&s_B[tb + s][4];
            *(float4*)&Bv[8]  = *(const float4*)&s_B[tb + s][8];
            *(float4*)&Bv[12] = *(const float4*)&s_B[tb + s][12];
            *(float4*)&Cv[0]  = *(const float4*)&s_C[tb + s][0];
            *(float4*)&Cv[4]  = *(const float4*)&s_C[tb + s][4];
            *(float4*)&Cv[8]  = *(const float4*)&s_C[tb + s][8];
            *(float4*)&Cv[12] = *(const float4*)&s_C[tb + s][12];
            float du = dtv[s] * xvv[s];
            float y = 0.f;
#pragma unroll
            for (int n = 0; n < 16; ++n) {
                float dA = __expf(dtv[s] * An[n]);
                h[n] = fmaf(dA, h[n], du * Bv[n]);
                y = fmaf(h[n], Cv[n], y);
            }
            y = fmaf(xvv[s], Dd, y);
            float sz = zv[s] / (1.f + __expf(-zv[s]));
            yp[(size_t)(tb + s) * D_INNER] = f2bf(y * sz);
        }
    }
}

// ---------------------------------------------------------------------------
extern "C" void kernel_launch(void* const* d_in, const int* in_sizes, int n_in,
                              void* d_out, int out_size, void* d_ws, size_t ws_size,
                              hipStream_t stream) {
    const float* x          = (const float*)d_in[0];
    const float* in_proj_w  = (const float*)d_in[1];
    const float* conv_w     = (const float*)d_in[2];
    const float* conv_b     = (const float*)d_in[3];
    const float* x_proj_w   = (const float*)d_in[4];
    const float* dt_proj_w  = (const float*)d_in[5];
    const float* dt_proj_b  = (const float*)d_in[6];
    const float* A_log      = (const float*)d_in[7];
    const float* Dvec       = (const float*)d_in[8];
    const float* out_proj_w = (const float*)d_in[9];
    float* out = (float*)d_out;

    // f32 workspace regions
    float* xz     = (float*)d_ws;                          // 64MB
    float* xc_act = xz + (size_t)NROW * 2 * D_INNER;       // 32MB
    float* x_dbl  = xc_act + (size_t)NROW * D_INNER;       // 1.5MB
    float* dlt    = x_dbl + (size_t)NROW * XPROJ_N;        // 32MB
    // bf16 aliases with disjoint lifetimes:
    uint16_t* A1   = (uint16_t*)xc_act;                    // dead before conv_silu
    uint16_t* B1T  = (uint16_t*)x_dbl;                     // dead before xdbl_gemm
    uint16_t* ygb  = (uint16_t*)(dlt + (size_t)NROW * D_INNER);  // 16MB fresh
    uint16_t* opwT = ygb + (size_t)NROW * D_INNER;               //  4MB fresh

    // allow 128 KB dynamic LDS for the 8-phase GEMM (host-side, capture-safe)
    (void)hipFuncSetAttribute((const void*)gemm256_8p,
                              hipFuncAttributeMaxDynamicSharedMemorySize, 131072);

    // 1) split-bf16 operand prep for GEMM1
    cvt_x_split<<<(NROW * D_MODEL / 4) / 256, 256, 0, stream>>>(x, A1);
    cvt_wT_split<<<dim3(D_MODEL / 32, (2 * D_INNER) / 32), 256, 0, stream>>>(in_proj_w, B1T);
    // 2) xz = x @ in_proj_w  via 256^2 8-phase bf16 MFMA, K' = 3072 exact split
    gemm256_8p<<<dim3(NROW / 256, (2 * D_INNER) / 256), 512, 131072, stream>>>(
        A1, B1T, xz, NROW, 2 * D_INNER, 3 * D_MODEL);
    // 3) conv + silu
    conv_silu<<<(NROW * D_INNER) / 256, 256, 0, stream>>>(xz, conv_w, conv_b, xc_act);
    // 4) x_dbl = xc_act @ x_proj_w
    xdbl_gemm<<<NROW / 32, 256, 0, stream>>>(xc_act, x_proj_w, x_dbl);
    // 5) dlt = softplus(x_dbl[:, :64] @ dt_proj_w + b)
    dt_gemm<<<dim3(NROW / 64, D_INNER / 64), 256, 0, stream>>>(x_dbl, dt_proj_w, dt_proj_b, dlt);
    // 6) chunked selective scan; pass3 writes y_gated directly as bf16
    scan_pass1<<<BATCH * NCHUNK * 8, 256, 0, stream>>>(dlt, xc_act, x_dbl, A_log, xz);
    scan_pass2<<<(BATCH * D_INNER * 16) / 256, 256, 0, stream>>>(xz);
    scan_pass3<<<BATCH * NCHUNK * 8, 256, 0, stream>>>(dlt, xc_act, x_dbl, xz,
                                                       A_log, Dvec, xz, ygb);
    // 7) out-projection operand prep + bf16 GEMM2 (skinny-N tile)
    cvt_opwT<<<dim3(D_INNER / 32, D_MODEL / 32), 256, 0, stream>>>(out_proj_w, opwT);
    gemm_bf16_bt<64><<<dim3(NROW / 128, D_MODEL / 64), 256, 0, stream>>>(
        ygb, opwT, out, NROW, D_MODEL, D_INNER);
}

// Round 9
// 349.299 us; speedup vs baseline: 1.3705x; 1.1948x over previous
//
#include <hip/hip_runtime.h>
#include <hip/hip_bf16.h>
#include <stdint.h>

#define D_MODEL 1024
#define D_STATE 16
#define D_CONV 4
#define D_INNER 2048
#define DT_RANK 64
#define BATCH 2
#define SEQ 2048
#define NROW (BATCH * SEQ)          // 4096
#define XPROJ_N (DT_RANK + 2 * D_STATE)  // 96
#define NCHUNK 64                   // time chunks for scan decomposition
#define CL 32                       // SEQ / NCHUNK

typedef __bf16 bf16x8 __attribute__((ext_vector_type(8)));
typedef float  f32x4  __attribute__((ext_vector_type(4)));

// RNE f32 -> bf16 (bit trick; inputs are tame, no NaN handling needed)
__device__ __forceinline__ uint16_t f2bf(float f) {
    uint32_t u = __float_as_uint(f);
    u += 0x7FFFu + ((u >> 16) & 1u);
    return (uint16_t)(u >> 16);
}
__device__ __forceinline__ float bf2f(uint16_t h) {
    return __uint_as_float((uint32_t)h << 16);
}

#define GLOAD_LDS(g, l) __builtin_amdgcn_global_load_lds(                      \
    (const __attribute__((address_space(1))) void*)(g),                        \
    (__attribute__((address_space(3))) void*)(l), 16, 0, 0)

// ===========================================================================
// 256x256 8-phase bf16 GEMM (R8: bank-conflict-free swizzle, conflicts == 0).
// Frozen this round. ~132 us, 780 TF, MfmaUtil 31%.
// ===========================================================================
#define LDA8(BUF, MH) do {                                                     \
  _Pragma("unroll") for (int m_ = 0; m_ < 4; ++m_)                             \
    _Pragma("unroll") for (int ks_ = 0; ks_ < 2; ++ks_) {                      \
      int e_ = (((MH)*64 + m_*16 + fr) << 6) + ks_*32 + fg*8;                  \
      e_ ^= ((e_ >> 6) & 7) << 3;                                              \
      a[m_][ks_] = *(const bf16x8*)&lds[(BUF)*32768 + wm*8192 + e_];           \
    }                                                                          \
} while (0)

#define LDB4(BUF, NH) do {                                                     \
  _Pragma("unroll") for (int n_ = 0; n_ < 2; ++n_)                             \
    _Pragma("unroll") for (int ks_ = 0; ks_ < 2; ++ks_) {                      \
      int e_ = ((((wn & 1)*64) + (NH)*32 + n_*16 + fr) << 6) + ks_*32 + fg*8;  \
      e_ ^= ((e_ >> 6) & 7) << 3;                                              \
      bb[NH][n_][ks_] = *(const bf16x8*)&lds[(BUF)*32768 + 16384 +             \
                                             (wn >> 1)*8192 + e_];             \
    }                                                                          \
} while (0)

#define MFMA16(MH, NH) do {                                                    \
  __builtin_amdgcn_s_setprio(1);                                               \
  _Pragma("unroll") for (int m_ = 0; m_ < 4; ++m_)                             \
    _Pragma("unroll") for (int n_ = 0; n_ < 2; ++n_)                           \
      _Pragma("unroll") for (int ks_ = 0; ks_ < 2; ++ks_)                      \
        acc[(MH)*4 + m_][(NH)*2 + n_] = __builtin_amdgcn_mfma_f32_16x16x32_bf16( \
            a[m_][ks_], bb[NH][n_][ks_], acc[(MH)*4 + m_][(NH)*2 + n_], 0, 0, 0); \
  __builtin_amdgcn_s_setprio(0);                                               \
} while (0)

#define STAGE(MAT, HALF, T) do {                                               \
  if ((T) < NT) {                                                              \
    const uint16_t* s0_ = ((MAT) ? Bs0 : As0) + (size_t)(HALF)*128*K + (size_t)(T)*64; \
    const uint16_t* s1_ = ((MAT) ? Bs1 : As1) + (size_t)(HALF)*128*K + (size_t)(T)*64; \
    uint16_t* d_ = lds + (((T) & 1)*32768 + (MAT)*16384 + (HALF)*8192 + wave*512); \
    GLOAD_LDS(s0_, d_);                                                        \
    GLOAD_LDS(s1_, d_ + 4096);                                                 \
  }                                                                            \
} while (0)

#define BAR()  __builtin_amdgcn_s_barrier()
#define LGKM0() do { asm volatile("s_waitcnt lgkmcnt(0)" ::: "memory");        \
                     __builtin_amdgcn_sched_barrier(0); } while (0)
#define VM4()  do { asm volatile("s_waitcnt vmcnt(4)" ::: "memory");           \
                    __builtin_amdgcn_sched_barrier(0); } while (0)

__global__ __launch_bounds__(512, 2) void gemm256_8p(const uint16_t* __restrict__ A,
                                                     const uint16_t* __restrict__ BT,
                                                     float* __restrict__ C,
                                                     int M, int N, int K) {
    extern __shared__ uint16_t lds[];           // 131072 bytes
    const int tid  = threadIdx.x;
    const int wave = tid >> 6, lane = tid & 63;
    const int wm = wave >> 2, wn = wave & 3;    // 2M x 4N wave grid
    const int fr = lane & 15, fg = lane >> 4;
    const int bm = blockIdx.x * 256, bn = blockIdx.y * 256;
    const int NT = K >> 6;                      // number of K-tiles (BK=64)
    const int NIT = NT >> 1;

    const int srow = wave * 8 + (lane >> 3);
    const int skcol = (((lane & 7) ^ ((lane >> 3) & 7)) * 8);
    const uint16_t* As0 = A  + (size_t)(bm + srow) * K + skcol;
    const uint16_t* As1 = A  + (size_t)(bm + srow + 64) * K + skcol;
    const uint16_t* Bs0 = BT + (size_t)(bn + srow) * K + skcol;
    const uint16_t* Bs1 = BT + (size_t)(bn + srow + 64) * K + skcol;

    f32x4 acc[8][4] = {};
    bf16x8 a[4][2];
    bf16x8 bb[2][2][2];

    STAGE(0, 0, 0); STAGE(0, 1, 0); STAGE(1, 0, 0); STAGE(1, 1, 0);
    STAGE(1, 0, 1); STAGE(1, 1, 1);
    VM4(); BAR();

    for (int i = 0; i < NIT; ++i) {
        const int T0 = 2 * i, T1 = 2 * i + 1;
        LDA8(0, 0); LDB4(0, 0); STAGE(0, 0, T1);
        BAR(); LGKM0(); MFMA16(0, 0); BAR();
        LDB4(0, 1);             STAGE(0, 1, T1);
        BAR(); LGKM0(); MFMA16(0, 1); BAR();
        LDA8(0, 1);             STAGE(1, 0, T0 + 2);
        BAR(); LGKM0(); MFMA16(1, 0); BAR();
                                STAGE(1, 1, T0 + 2);
        VM4();
        BAR(); LGKM0(); MFMA16(1, 1); BAR();
        LDA8(1, 0); LDB4(1, 0); STAGE(0, 0, T0 + 2);
        BAR(); LGKM0(); MFMA16(0, 0); BAR();
        LDB4(1, 1);             STAGE(0, 1, T0 + 2);
        BAR(); LGKM0(); MFMA16(0, 1); BAR();
        LDA8(1, 1);             STAGE(1, 0, T1 + 2);
        BAR(); LGKM0(); MFMA16(1, 0); BAR();
                                STAGE(1, 1, T1 + 2);
        VM4();
        BAR(); LGKM0(); MFMA16(1, 1); BAR();
    }

    const int crow0 = bm + wm * 128 + fg * 4;
    const int ccol0 = bn + wn * 64 + fr;
#pragma unroll
    for (int mp = 0; mp < 8; ++mp)
#pragma unroll
        for (int np = 0; np < 4; ++np)
#pragma unroll
            for (int r = 0; r < 4; ++r)
                C[(size_t)(crow0 + mp * 16 + r) * N + ccol0 + np * 16] = acc[mp][np][r];
}

// ---------------------------------------------------------------------------
// m97-structure bf16 GEMM for skinny N (GEMM2). BN=64: 4x1 waves, 32x64/wave.
// ---------------------------------------------------------------------------
template <int BN>
__global__ __launch_bounds__(256) void gemm_bf16_bt(const uint16_t* __restrict__ A,
                                                    const uint16_t* __restrict__ BT,
                                                    float* __restrict__ C,
                                                    int M, int N, int K) {
    constexpr int WROWS = (BN == 128) ? 64 : 32;
    constexpr int MF = WROWS / 16;
    __shared__ uint16_t sA[128 * 32];
    __shared__ uint16_t sB[BN * 32];
    const int tid  = threadIdx.x;
    const int wave = tid >> 6;
    const int lane = tid & 63;
    const int wm = (BN == 128) ? (wave >> 1) : wave;
    const int wn = (BN == 128) ? (wave & 1) : 0;
    const int bm = blockIdx.x * 128;
    const int bn = blockIdx.y * BN;

    const int lrow = lane >> 2;
    const int lcol = (lane & 3) * 8;
    const uint16_t* gA0 = A + (size_t)(bm + wave * 32 + lrow) * K + lcol;
    const uint16_t* gA1 = gA0 + (size_t)16 * K;
    uint16_t* lA0 = sA + (wave * 2 + 0) * 512;
    uint16_t* lA1 = sA + (wave * 2 + 1) * 512;
    const uint16_t* gB0;
    const uint16_t* gB1 = nullptr;
    uint16_t* lB0;
    uint16_t* lB1 = nullptr;
    if constexpr (BN == 128) {
        gB0 = BT + (size_t)(bn + wave * 32 + lrow) * K + lcol;
        gB1 = gB0 + (size_t)16 * K;
        lB0 = sB + (wave * 2 + 0) * 512;
        lB1 = sB + (wave * 2 + 1) * 512;
    } else {
        gB0 = BT + (size_t)(bn + wave * 16 + lrow) * K + lcol;
        lB0 = sB + wave * 512;
    }

    const int fr = lane & 15;
    const int fg = lane >> 4;

    f32x4 acc[MF][4] = {};

    for (int k0 = 0; k0 < K; k0 += 32) {
        GLOAD_LDS(gA0 + k0, lA0);
        GLOAD_LDS(gA1 + k0, lA1);
        GLOAD_LDS(gB0 + k0, lB0);
        if constexpr (BN == 128) GLOAD_LDS(gB1 + k0, lB1);
        __syncthreads();

        bf16x8 af[MF], bfr[4];
#pragma unroll
        for (int m = 0; m < MF; ++m)
            af[m] = *(const bf16x8*)&sA[(wm * WROWS + m * 16 + fr) * 32 + fg * 8];
#pragma unroll
        for (int n = 0; n < 4; ++n)
            bfr[n] = *(const bf16x8*)&sB[(wn * 64 + n * 16 + fr) * 32 + fg * 8];
#pragma unroll
        for (int m = 0; m < MF; ++m)
#pragma unroll
            for (int n = 0; n < 4; ++n)
                acc[m][n] = __builtin_amdgcn_mfma_f32_16x16x32_bf16(
                    af[m], bfr[n], acc[m][n], 0, 0, 0);
        __syncthreads();
    }

#pragma unroll
    for (int m = 0; m < MF; ++m)
#pragma unroll
        for (int n = 0; n < 4; ++n) {
            const int col = bn + wn * 64 + n * 16 + fr;
#pragma unroll
            for (int r = 0; r < 4; ++r) {
                const int row = bm + wm * WROWS + m * 16 + fg * 4 + r;
                C[(size_t)row * N + col] = acc[m][n][r];
            }
        }
}

// ---------------------------------------------------------------------------
// xdbl MFMA, K-split: grid (M/128, 8). Block (bx,ks) computes partial
// part[ks] (4096x128) = xcb[:, ks*256:(ks+1)*256] @ xpwT^T. BK=32, 8 iters.
// Only cols 0..95 are meaningful (xpwT rows 96..127 are zero).
// ---------------------------------------------------------------------------
__global__ __launch_bounds__(256) void xdbl_mfma(const uint16_t* __restrict__ A,
                                                 const uint16_t* __restrict__ BT,
                                                 float* __restrict__ part) {
    __shared__ uint16_t sA[128 * 32];
    __shared__ uint16_t sB[128 * 32];
    const int tid  = threadIdx.x;
    const int wave = tid >> 6;
    const int lane = tid & 63;
    const int wm = wave >> 1, wn = wave & 1;
    const int bm = blockIdx.x * 128;
    const int koff = blockIdx.y * 256;

    const int lrow = lane >> 2;
    const int lcol = (lane & 3) * 8;
    const uint16_t* gA0 = A + (size_t)(bm + wave * 32 + lrow) * D_INNER + koff + lcol;
    const uint16_t* gA1 = gA0 + (size_t)16 * D_INNER;
    const uint16_t* gB0 = BT + (size_t)(wave * 32 + lrow) * D_INNER + koff + lcol;
    const uint16_t* gB1 = gB0 + (size_t)16 * D_INNER;
    uint16_t* lA0 = sA + (wave * 2 + 0) * 512;
    uint16_t* lA1 = sA + (wave * 2 + 1) * 512;
    uint16_t* lB0 = sB + (wave * 2 + 0) * 512;
    uint16_t* lB1 = sB + (wave * 2 + 1) * 512;

    const int fr = lane & 15;
    const int fg = lane >> 4;

    f32x4 acc[4][4] = {};

    for (int k0 = 0; k0 < 256; k0 += 32) {
        GLOAD_LDS(gA0 + k0, lA0);
        GLOAD_LDS(gA1 + k0, lA1);
        GLOAD_LDS(gB0 + k0, lB0);
        GLOAD_LDS(gB1 + k0, lB1);
        __syncthreads();
        bf16x8 af[4], bfr[4];
#pragma unroll
        for (int m = 0; m < 4; ++m)
            af[m] = *(const bf16x8*)&sA[(wm * 64 + m * 16 + fr) * 32 + fg * 8];
#pragma unroll
        for (int n = 0; n < 4; ++n)
            bfr[n] = *(const bf16x8*)&sB[(wn * 64 + n * 16 + fr) * 32 + fg * 8];
#pragma unroll
        for (int m = 0; m < 4; ++m)
#pragma unroll
            for (int n = 0; n < 4; ++n)
                acc[m][n] = __builtin_amdgcn_mfma_f32_16x16x32_bf16(
                    af[m], bfr[n], acc[m][n], 0, 0, 0);
        __syncthreads();
    }

    float* P = part + (size_t)blockIdx.y * NROW * 128;
#pragma unroll
    for (int m = 0; m < 4; ++m)
#pragma unroll
        for (int n = 0; n < 4; ++n) {
            const int col = wn * 64 + n * 16 + fr;
#pragma unroll
            for (int r = 0; r < 4; ++r) {
                const int row = bm + wm * 64 + m * 16 + fg * 4 + r;
                P[(size_t)row * 128 + col] = acc[m][n][r];
            }
        }
}

// x_dbl[r][c] = sum_ks part[ks][r][c]   (c in 0..95, float4 groups)
__global__ __launch_bounds__(256) void xdbl_reduce(const float* __restrict__ part,
                                                   float* __restrict__ xdbl) {
    const int i = blockIdx.x * 256 + threadIdx.x;   // over 4096*24 float4
    const int r = i / 24, c4 = (i % 24) * 4;
    f32x4 s = {};
#pragma unroll
    for (int ks = 0; ks < 8; ++ks)
        s += *(const f32x4*)&part[(size_t)ks * NROW * 128 + (size_t)r * 128 + c4];
    *(f32x4*)&xdbl[(size_t)r * XPROJ_N + c4] = s;
}

// ---------------------------------------------------------------------------
// x (4096x1024 f32) -> A' (4096x3072 bf16) = [hi | lo | hi]
// ---------------------------------------------------------------------------
__global__ __launch_bounds__(256) void cvt_x_split(const float* __restrict__ x,
                                                   uint16_t* __restrict__ a1) {
    const int i = blockIdx.x * 256 + threadIdx.x;
    const int m = i >> 8;
    const int c = (i & 255) << 2;
    const float4 v = ((const float4*)x)[i];
    uint16_t h[4], l[4];
    const float vf[4] = {v.x, v.y, v.z, v.w};
#pragma unroll
    for (int j = 0; j < 4; ++j) {
        h[j] = f2bf(vf[j]);
        l[j] = f2bf(vf[j] - bf2f(h[j]));
    }
    const size_t base = (size_t)m * 3072 + c;
    *(ushort4*)&a1[base]        = *(ushort4*)h;
    *(ushort4*)&a1[base + 1024] = *(ushort4*)l;
    *(ushort4*)&a1[base + 2048] = *(ushort4*)h;
}

// ---------------------------------------------------------------------------
// in_proj_w (1024x4096 f32) -> B'T (4096x3072 bf16): row n = [hi | hi | lo]
// ---------------------------------------------------------------------------
__global__ __launch_bounds__(256) void cvt_wT_split(const float* __restrict__ w,
                                                    uint16_t* __restrict__ bt) {
    __shared__ float s[32][33];
    const int tid = threadIdx.x;
    const int k0 = blockIdx.x * 32;
    const int n0 = blockIdx.y * 32;
#pragma unroll
    for (int p = 0; p < 4; ++p) {
        int lin = tid + p * 256;
        int i = lin >> 5, j = lin & 31;
        s[i][j] = w[(size_t)(k0 + i) * 4096 + n0 + j];
    }
    __syncthreads();
    const int r = tid >> 3, c4 = (tid & 7) * 4;
    uint16_t h[4], l[4];
#pragma unroll
    for (int j = 0; j < 4; ++j) {
        float v = s[c4 + j][r];
        h[j] = f2bf(v);
        l[j] = f2bf(v - bf2f(h[j]));
    }
    const size_t base = (size_t)(n0 + r) * 3072 + k0 + c4;
    *(ushort4*)&bt[base]        = *(ushort4*)h;
    *(ushort4*)&bt[base + 1024] = *(ushort4*)h;
    *(ushort4*)&bt[base + 2048] = *(ushort4*)l;
}

// ---------------------------------------------------------------------------
// out_proj_w (2048x1024 f32) -> opwT (1024x2048 bf16), plain hi.
// ---------------------------------------------------------------------------
__global__ __launch_bounds__(256) void cvt_opwT(const float* __restrict__ w,
                                                uint16_t* __restrict__ bt) {
    __shared__ float s[32][33];
    const int tid = threadIdx.x;
    const int k0 = blockIdx.x * 32;
    const int n0 = blockIdx.y * 32;
#pragma unroll
    for (int p = 0; p < 4; ++p) {
        int lin = tid + p * 256;
        int i = lin >> 5, j = lin & 31;
        s[i][j] = w[(size_t)(k0 + i) * 1024 + n0 + j];
    }
    __syncthreads();
    const int r = tid >> 3, c4 = (tid & 7) * 4;
    uint16_t h[4];
#pragma unroll
    for (int j = 0; j < 4; ++j) h[j] = f2bf(s[c4 + j][r]);
    *(ushort4*)&bt[(size_t)(n0 + r) * 2048 + k0 + c4] = *(ushort4*)h;
}

// ---------------------------------------------------------------------------
// x_proj_w (2048x96 f32) -> xpwT (128x2048 bf16), rows 96..127 = 0.
// ---------------------------------------------------------------------------
__global__ __launch_bounds__(256) void cvt_xpwT(const float* __restrict__ w,
                                                uint16_t* __restrict__ bt) {
    __shared__ float s[32][33];
    const int tid = threadIdx.x;
    const int k0 = blockIdx.x * 32;   // K rows (2048)
    const int n0 = blockIdx.y * 32;   // out cols (0..127)
#pragma unroll
    for (int p = 0; p < 4; ++p) {
        int lin = tid + p * 256;
        int i = lin >> 5, j = lin & 31;
        s[i][j] = (n0 + j < XPROJ_N) ? w[(size_t)(k0 + i) * XPROJ_N + n0 + j] : 0.f;
    }
    __syncthreads();
    const int r = tid >> 3, c4 = (tid & 7) * 4;
    uint16_t h[4];
#pragma unroll
    for (int j = 0; j < 4; ++j) h[j] = f2bf(s[c4 + j][r]);
    *(ushort4*)&bt[(size_t)(n0 + r) * D_INNER + k0 + c4] = *(ushort4*)h;
}

// ---------------------------------------------------------------------------
// Causal depthwise conv (D_CONV=4) + bias + SiLU; writes BF16.
// ---------------------------------------------------------------------------
__global__ __launch_bounds__(256) void conv_silu(const float* __restrict__ xz,
                                                 const float* __restrict__ conv_w,
                                                 const float* __restrict__ conv_b,
                                                 uint16_t* __restrict__ xcb) {
    int idx = blockIdx.x * 256 + threadIdx.x;
    int d = idx & (D_INNER - 1);
    int r = idx >> 11;
    int t = r & (SEQ - 1);
    float acc = conv_b[d];
#pragma unroll
    for (int k = 0; k < D_CONV; ++k) {
        int tt = t + k - (D_CONV - 1);
        if (tt >= 0)
            acc = fmaf(xz[(size_t)(r + k - (D_CONV - 1)) * (2 * D_INNER) + d],
                       conv_w[d * D_CONV + k], acc);
    }
    float s = acc / (1.f + __expf(-acc));
    xcb[(size_t)r * D_INNER + d] = f2bf(s);
}

// ---------------------------------------------------------------------------
// dlt = softplus(x_dbl[:, :64] @ dt_proj_w + dt_proj_b).  K=64, tiles 64x64.
// ---------------------------------------------------------------------------
__global__ __launch_bounds__(256) void dt_gemm(const float* __restrict__ xdbl,
                                               const float* __restrict__ W,
                                               const float* __restrict__ bias,
                                               float* __restrict__ out) {
    __shared__ float As[64][68];
    __shared__ float Ws[64][64];
    const int tid = threadIdx.x;
    const int bm = blockIdx.x * 64, bn = blockIdx.y * 64;
#pragma unroll
    for (int l = 0; l < 4; ++l) {
        int i = tid + l * 256;
        int r = i >> 4, q4 = (i & 15) << 2;
        float4 v = *(const float4*)(xdbl + (size_t)(bm + r) * XPROJ_N + q4);
        As[q4 + 0][r] = v.x; As[q4 + 1][r] = v.y; As[q4 + 2][r] = v.z; As[q4 + 3][r] = v.w;
    }
#pragma unroll
    for (int l = 0; l < 4; ++l) {
        int i = tid + l * 256;
        int q = i >> 4, c4 = (i & 15) << 2;
        *(float4*)&Ws[q][c4] = *(const float4*)(W + (size_t)q * D_INNER + bn + c4);
    }
    __syncthreads();
    const int tx = tid & 15, ty = tid >> 4;
    float acc[4][4];
#pragma unroll
    for (int i = 0; i < 4; ++i)
#pragma unroll
        for (int j = 0; j < 4; ++j) acc[i][j] = 0.f;
#pragma unroll 16
    for (int k = 0; k < 64; ++k) {
        float a[4], w[4];
        *(float4*)a = *(const float4*)&As[k][ty * 4];
        *(float4*)w = *(const float4*)&Ws[k][tx * 4];
#pragma unroll
        for (int i = 0; i < 4; ++i)
#pragma unroll
            for (int j = 0; j < 4; ++j)
                acc[i][j] = fmaf(a[i], w[j], acc[i][j]);
    }
#pragma unroll
    for (int i = 0; i < 4; ++i) {
#pragma unroll
        for (int j = 0; j < 4; ++j) {
            float v = acc[i][j] + bias[bn + tx * 4 + j];
            float sp = fmaxf(v, 0.f) + log1pf(__expf(-fabsf(v)));
            out[(size_t)(bm + ty * 4 + i) * D_INNER + bn + tx * 4 + j] = sp;
        }
    }
}

// ---------------------------------------------------------------------------
// Chunked selective scan; carries live in the dead xc-half of xz.
// ---------------------------------------------------------------------------
__device__ __forceinline__ size_t hole(size_t i) {
    return (i >> 11) * 4096 + (i & 2047);
}

__global__ __launch_bounds__(256) void scan_pass1(const float* __restrict__ dlt,
                                                  const uint16_t* __restrict__ xcb,
                                                  const float* __restrict__ xdbl,
                                                  const float* __restrict__ A_log,
                                                  float* __restrict__ carry) {
    __shared__ float s_B[CL][16];
    const int tid = threadIdx.x;
    const int bid = blockIdx.x;
    const int dg = bid & 7;
    const int c  = (bid >> 3) & (NCHUNK - 1);
    const int b  = bid >> 9;
    const int d  = dg * 256 + tid;
    const size_t rowbase = (size_t)b * SEQ + c * CL;

    float An[16];
    {
        float tmp[16];
        *(float4*)&tmp[0]  = *(const float4*)&A_log[d * 16 + 0];
        *(float4*)&tmp[4]  = *(const float4*)&A_log[d * 16 + 4];
        *(float4*)&tmp[8]  = *(const float4*)&A_log[d * 16 + 8];
        *(float4*)&tmp[12] = *(const float4*)&A_log[d * 16 + 12];
#pragma unroll
        for (int n = 0; n < 16; ++n) An[n] = -__expf(tmp[n]);
    }

#pragma unroll
    for (int p = 0; p < CL * 16 / 256; ++p) {
        int i = tid + p * 256;
        int t = i >> 4, n = i & 15;
        s_B[t][n] = xdbl[(rowbase + t) * (size_t)XPROJ_N + DT_RANK + n];
    }
    __syncthreads();

    float h[16], pA[16];
#pragma unroll
    for (int n = 0; n < 16; ++n) { h[n] = 0.f; pA[n] = 1.f; }

    const float* dtp = dlt + rowbase * D_INNER + d;
    const uint16_t* xvp = xcb + rowbase * D_INNER + d;

    for (int tb = 0; tb < CL; tb += 4) {
        float dtv[4], xvv[4];
#pragma unroll
        for (int s = 0; s < 4; ++s) {
            dtv[s] = dtp[(size_t)(tb + s) * D_INNER];
            xvv[s] = bf2f(xvp[(size_t)(tb + s) * D_INNER]);
        }
#pragma unroll
        for (int s = 0; s < 4; ++s) {
            float Bv[16];
            *(float4*)&Bv[0]  = *(const float4*)&s_B[tb + s][0];
            *(float4*)&Bv[4]  = *(const float4*)&s_B[tb + s][4];
            *(float4*)&Bv[8]  = *(const float4*)&s_B[tb + s][8];
            *(float4*)&Bv[12] = *(const float4*)&s_B[tb + s][12];
            float du = dtv[s] * xvv[s];
#pragma unroll
            for (int n = 0; n < 16; ++n) {
                float dA = __expf(dtv[s] * An[n]);
                pA[n] *= dA;
                h[n] = fmaf(dA, h[n], du * Bv[n]);
            }
        }
    }

    size_t ci = (((size_t)b * NCHUNK + c) * D_INNER + d) * 16;
    float* pp = carry + hole(ci);
    float* hp = carry + hole(ci + ((size_t)1 << 22));
    *(float4*)&pp[0]  = *(float4*)&pA[0];  *(float4*)&pp[4]  = *(float4*)&pA[4];
    *(float4*)&pp[8]  = *(float4*)&pA[8];  *(float4*)&pp[12] = *(float4*)&pA[12];
    *(float4*)&hp[0]  = *(float4*)&h[0];   *(float4*)&hp[4]  = *(float4*)&h[4];
    *(float4*)&hp[8]  = *(float4*)&h[8];   *(float4*)&hp[12] = *(float4*)&h[12];
}

__global__ __launch_bounds__(256) void scan_pass2(float* __restrict__ carry) {
    int idx = blockIdx.x * 256 + threadIdx.x;
    int n = idx & 15;
    int d = (idx >> 4) & (D_INNER - 1);
    int b = idx >> 15;
    float prev = 0.f;
    for (int c = 0; c < NCHUNK; ++c) {
        size_t ci = (((size_t)b * NCHUNK + c) * D_INNER + d) * 16 + n;
        size_t op = hole(ci);
        size_t oh = op + (size_t)2048 * 4096;
        float p = carry[op];
        float e = carry[oh];
        carry[oh] = prev;
        prev = fmaf(p, prev, e);
    }
}

__global__ __launch_bounds__(256) void scan_pass3(const float* __restrict__ dlt,
                                                  const uint16_t* __restrict__ xcb,
                                                  const float* __restrict__ xdbl,
                                                  const float* __restrict__ xz,
                                                  const float* __restrict__ A_log,
                                                  const float* __restrict__ Dvec,
                                                  const float* __restrict__ carry,
                                                  uint16_t* __restrict__ ygb) {
    __shared__ float s_B[CL][16];
    __shared__ float s_C[CL][16];
    const int tid = threadIdx.x;
    const int bid = blockIdx.x;
    const int dg = bid & 7;
    const int c  = (bid >> 3) & (NCHUNK - 1);
    const int b  = bid >> 9;
    const int d  = dg * 256 + tid;
    const size_t rowbase = (size_t)b * SEQ + c * CL;

    float An[16];
    {
        float tmp[16];
        *(float4*)&tmp[0]  = *(const float4*)&A_log[d * 16 + 0];
        *(float4*)&tmp[4]  = *(const float4*)&A_log[d * 16 + 4];
        *(float4*)&tmp[8]  = *(const float4*)&A_log[d * 16 + 8];
        *(float4*)&tmp[12] = *(const float4*)&A_log[d * 16 + 12];
#pragma unroll
        for (int n = 0; n < 16; ++n) An[n] = -__expf(tmp[n]);
    }
    const float Dd = Dvec[d];

#pragma unroll
    for (int p = 0; p < CL * 32 / 256; ++p) {
        int i = tid + p * 256;
        int t = i >> 5, col = i & 31;
        float v = xdbl[(rowbase + t) * (size_t)XPROJ_N + DT_RANK + col];
        if (col < 16) s_B[t][col] = v;
        else          s_C[t][col - 16] = v;
    }
    __syncthreads();

    float h[16];
    {
        size_t ci = (((size_t)b * NCHUNK + c) * D_INNER + d) * 16;
        const float* hp = carry + hole(ci + ((size_t)1 << 22));
        *(float4*)&h[0]  = *(const float4*)&hp[0];
        *(float4*)&h[4]  = *(const float4*)&hp[4];
        *(float4*)&h[8]  = *(const float4*)&hp[8];
        *(float4*)&h[12] = *(const float4*)&hp[12];
    }

    const float* dtp = dlt + rowbase * D_INNER + d;
    const uint16_t* xvp = xcb + rowbase * D_INNER + d;
    const float* zp  = xz + rowbase * (size_t)(2 * D_INNER) + D_INNER + d;
    uint16_t* yp = ygb + rowbase * D_INNER + d;

    for (int tb = 0; tb < CL; tb += 4) {
        float dtv[4], xvv[4], zv[4];
#pragma unroll
        for (int s = 0; s < 4; ++s) {
            dtv[s] = dtp[(size_t)(tb + s) * D_INNER];
            xvv[s] = bf2f(xvp[(size_t)(tb + s) * D_INNER]);
            zv[s]  = zp[(size_t)(tb + s) * (2 * D_INNER)];
        }
#pragma unroll
        for (int s = 0; s < 4; ++s) {
            float Bv[16], Cv[16];
            *(float4*)&Bv[0]  = *(const float4*)&s_B[tb + s][0];
            *(float4*)&Bv[4]  = *(const float4*)&s_B[tb + s][4];
            *(float4*)&Bv[8]  = *(const float4*)&s_B[tb + s][8];
            *(float4*)&Bv[12] = *(const float4*)&s_B[tb + s][12];
            *(float4*)&Cv[0]  = *(const float4*)&s_C[tb + s][0];
            *(float4*)&Cv[4]  = *(const float4*)&s_C[tb + s][4];
            *(float4*)&Cv[8]  = *(const float4*)&s_C[tb + s][8];
            *(float4*)&Cv[12] = *(const float4*)&s_C[tb + s][12];
            float du = dtv[s] * xvv[s];
            float y = 0.f;
#pragma unroll
            for (int n = 0; n < 16; ++n) {
                float dA = __expf(dtv[s] * An[n]);
                h[n] = fmaf(dA, h[n], du * Bv[n]);
                y = fmaf(h[n], Cv[n], y);
            }
            y = fmaf(xvv[s], Dd, y);
            float sz = zv[s] / (1.f + __expf(-zv[s]));
            yp[(size_t)(tb + s) * D_INNER] = f2bf(y * sz);
        }
    }
}

// ---------------------------------------------------------------------------
extern "C" void kernel_launch(void* const* d_in, const int* in_sizes, int n_in,
                              void* d_out, int out_size, void* d_ws, size_t ws_size,
                              hipStream_t stream) {
    const float* x          = (const float*)d_in[0];
    const float* in_proj_w  = (const float*)d_in[1];
    const float* conv_w     = (const float*)d_in[2];
    const float* conv_b     = (const float*)d_in[3];
    const float* x_proj_w   = (const float*)d_in[4];
    const float* dt_proj_w  = (const float*)d_in[5];
    const float* dt_proj_b  = (const float*)d_in[6];
    const float* A_log      = (const float*)d_in[7];
    const float* Dvec       = (const float*)d_in[8];
    const float* out_proj_w = (const float*)d_in[9];
    float* out = (float*)d_out;

    // f32 workspace regions (same footprint as R4-R8)
    float* xz     = (float*)d_ws;                          // 64MB
    float* xc_reg = xz + (size_t)NROW * 2 * D_INNER;       // 32MB region
    float* x_dbl  = xc_reg + (size_t)NROW * D_INNER;       // 1.5MB
    float* dlt    = x_dbl + (size_t)NROW * XPROJ_N;        // 32MB
    // aliases with disjoint lifetimes:
    uint16_t* A1   = (uint16_t*)xc_reg;                    // 24MB, dead after GEMM1
    uint16_t* B1T  = (uint16_t*)x_dbl;                     // 24MB (spans into dlt), dead after GEMM1
    uint16_t* xcb  = (uint16_t*)xc_reg;                    // 16MB bf16 xc (written after GEMM1)
    float* part    = (float*)((char*)xc_reg + (size_t)16 * 1024 * 1024); // 16MB (8 x 4096 x 128 f32)
    uint16_t* xpwT = (uint16_t*)((char*)x_dbl + (size_t)2 * 1024 * 1024); // 0.5MB, dead before dlt write
    uint16_t* ygb  = (uint16_t*)(dlt + (size_t)NROW * D_INNER);  // 16MB fresh
    uint16_t* opwT = ygb + (size_t)NROW * D_INNER;               //  4MB fresh

    (void)hipFuncSetAttribute((const void*)gemm256_8p,
                              hipFuncAttributeMaxDynamicSharedMemorySize, 131072);

    // 1) split-bf16 operand prep for GEMM1
    cvt_x_split<<<(NROW * D_MODEL / 4) / 256, 256, 0, stream>>>(x, A1);
    cvt_wT_split<<<dim3(D_MODEL / 32, (2 * D_INNER) / 32), 256, 0, stream>>>(in_proj_w, B1T);
    // 2) xz = x @ in_proj_w  via 256^2 8-phase bf16 MFMA, K' = 3072 exact split
    gemm256_8p<<<dim3(NROW / 256, (2 * D_INNER) / 256), 512, 131072, stream>>>(
        A1, B1T, xz, NROW, 2 * D_INNER, 3 * D_MODEL);
    // 3) conv + silu -> bf16 xc
    conv_silu<<<(NROW * D_INNER) / 256, 256, 0, stream>>>(xz, conv_w, conv_b, xcb);
    // 4) x_dbl = xc @ x_proj_w via bf16 MFMA, K-split 8 + reduce
    cvt_xpwT<<<dim3(D_INNER / 32, 4), 256, 0, stream>>>(x_proj_w, xpwT);
    xdbl_mfma<<<dim3(NROW / 128, 8), 256, 0, stream>>>(xcb, xpwT, part);
    xdbl_reduce<<<(NROW * 24) / 256, 256, 0, stream>>>(part, x_dbl);
    // 5) dlt = softplus(x_dbl[:, :64] @ dt_proj_w + b)
    dt_gemm<<<dim3(NROW / 64, D_INNER / 64), 256, 0, stream>>>(x_dbl, dt_proj_w, dt_proj_b, dlt);
    // 6) chunked selective scan; pass3 writes y_gated directly as bf16
    scan_pass1<<<BATCH * NCHUNK * 8, 256, 0, stream>>>(dlt, xcb, x_dbl, A_log, xz);
    scan_pass2<<<(BATCH * D_INNER * 16) / 256, 256, 0, stream>>>(xz);
    scan_pass3<<<BATCH * NCHUNK * 8, 256, 0, stream>>>(dlt, xcb, x_dbl, xz,
                                                       A_log, Dvec, xz, ygb);
    // 7) out-projection operand prep + bf16 GEMM2 (skinny-N tile)
    cvt_opwT<<<dim3(D_INNER / 32, D_MODEL / 32), 256, 0, stream>>>(out_proj_w, opwT);
    gemm_bf16_bt<64><<<dim3(NROW / 128, D_MODEL / 64), 256, 0, stream>>>(
        ygb, opwT, out, NROW, D_MODEL, D_INNER);
}